// Round 1
// baseline (398.210 us; speedup 1.0000x reference)
//
#include <hip/hip_runtime.h>

using f16 = _Float16;
using half8  = __attribute__((ext_vector_type(8))) f16;
using half4v = __attribute__((ext_vector_type(4))) f16;
using float4v = __attribute__((ext_vector_type(4))) float;

#define DEV static __device__ __forceinline__

constexpr int N = 2048, DIM = 1024, H = 16, DH = 64, F6 = 6144;
constexpr int LDSH = 136;       // f16 epilogue row stride (halves)
constexpr int TS = 128 * 128;   // packed tile elements
constexpr int NTILES = 136;     // triangular 128x128 tiles per head
constexpr int KD = 2048 * 64;   // D/C elements per T-slice per head

DEV int PL(int i, int k) { return i * (i + 1) / 2 + k; }                  // lower, k<=i
DEV int PU(int a, int b) { return a * 16 - a * (a - 1) / 2 + (b - a); }   // upper, a<=b

template<int ROWS, int THREADS>
DEV void stage64(const f16* __restrict__ g, int strideHalves, f16* lds, int tid) {
#pragma unroll
  for (int q = 0; q < (ROWS * 8) / THREADS; ++q) {
    const int chunk = q * THREADS + tid;
    const int m = chunk >> 3, c = (chunk & 7) ^ (m & 7);
    const f16* gp = g + (size_t)m * strideHalves + c * 8;
    __builtin_amdgcn_global_load_lds(
        (const __attribute__((address_space(1))) unsigned int*)gp,
        (__attribute__((address_space(3))) unsigned int*)(lds + chunk * 8), 16, 0, 0);
  }
}

DEV half8 rdfrag(const f16* T, int m, int ks, int q) {
  const int c = (ks * 4 + q) ^ (m & 7);
  return *(const half8*)(T + m * 64 + c * 8);
}

// store one element into frag layout (inverse of rdfrag addressing)
DEV void wfrag(f16* T, int row, int col, f16 v) {
  T[row * 64 + ((((col >> 3) ^ (row & 7)) << 3) | (col & 7))] = v;
}

DEV void gemm64(const f16* As, const f16* Bs, int wm, int wn, int l, float4v acc[4][4]) {
  const int q = l >> 4, mm = l & 15;
#pragma unroll
  for (int ks = 0; ks < 2; ++ks) {
    half8 af[4], bf[4];
#pragma unroll
    for (int mi = 0; mi < 4; ++mi) af[mi] = rdfrag(As, wm + mm + mi * 16, ks, q);
#pragma unroll
    for (int ni = 0; ni < 4; ++ni) bf[ni] = rdfrag(Bs, wn + mm + ni * 16, ks, q);
#pragma unroll
    for (int mi = 0; mi < 4; ++mi)
#pragma unroll
      for (int ni = 0; ni < 4; ++ni)
        acc[mi][ni] = __builtin_amdgcn_mfma_f32_16x16x32_f16(af[mi], bf[ni], acc[mi][ni], 0, 0, 0);
  }
}

// p in [0,136) -> (ti,tk), tk<=ti.
DEV void decode_pair(int p, int& ti, int& tk) {
  int t = (int)((sqrtf(8.f * p + 1.f) - 1.f) * 0.5f);
  while (t * (t + 1) / 2 > p) --t;
  while ((t + 1) * (t + 2) / 2 <= p) ++t;
  const int i2 = p - t * (t + 1) / 2;
  ti = (15 - t) + i2;
  tk = i2;
}

__global__ __launch_bounds__(256) void k_cast(const float* __restrict__ s, f16* __restrict__ d, int n4) {
  int i = blockIdx.x * 256 + threadIdx.x;
  if (i < n4) {
    float4 v = ((const float4*)s)[i];
    half4v h;
    h[0] = (f16)v.x; h[1] = (f16)v.y; h[2] = (f16)v.z; h[3] = (f16)v.w;
    ((half4v*)d)[i] = h;
  }
}

// qkvs = x @ w_qkv^T; per-head scatter. vu additionally stored transposed (vuT[h][d][n]).
__global__ __launch_bounds__(256) void k_qkv(const f16* __restrict__ xh, const f16* __restrict__ wh,
                                             f16* __restrict__ quh, f16* __restrict__ kuh,
                                             f16* __restrict__ vuh, f16* __restrict__ qch,
                                             f16* __restrict__ kch, f16* __restrict__ vcT,
                                             f16* __restrict__ vuT) {
  __shared__ __align__(16) f16 lds[128 * LDSH];
  f16* As = lds; f16* Bs = lds + 128 * 64;
  const int tid = threadIdx.x, w = tid >> 6, l = tid & 63;
  const int tm = blockIdx.x * 128, tf = blockIdx.y * 128;
  const int wm = (w >> 1) * 64, wn = (w & 1) * 64;
  float4v acc[4][4] = {};
  for (int k0 = 0; k0 < DIM; k0 += 64) {
    stage64<128, 256>(xh + (size_t)tm * DIM + k0, DIM, As, tid);
    stage64<128, 256>(wh + (size_t)tf * DIM + k0, DIM, Bs, tid);
    __syncthreads();
    gemm64(As, Bs, wm, wn, l, acc);
    __syncthreads();
  }
  const int rbase = (l >> 4) * 4, cidx = l & 15;
  const int t = tf >> 10;
  const float sc = (t == 0 || t == 3) ? 0.125f : 1.f;
  if (t == 5 || t == 2) {
    f16* T = (t == 5) ? vcT : vuT;
#pragma unroll
    for (int mi = 0; mi < 4; ++mi)
#pragma unroll
      for (int ni = 0; ni < 4; ++ni) {
        const int f = tf + wn + ni * 16 + cidx;
        const int h = (f & 1023) >> 6, d = f & 63;
        half4v p;
#pragma unroll
        for (int r = 0; r < 4; ++r) p[r] = (f16)acc[mi][ni][r];
        *(half4v*)(T + ((size_t)h * DH + d) * N + (tm + wm + mi * 16 + rbase)) = p;
      }
  }
  if (t != 5) {
#pragma unroll
    for (int mi = 0; mi < 4; ++mi)
#pragma unroll
      for (int ni = 0; ni < 4; ++ni)
#pragma unroll
        for (int r = 0; r < 4; ++r)
          lds[(wm + mi * 16 + rbase + r) * LDSH + wn + ni * 16 + cidx] = (f16)(acc[mi][ni][r] * sc);
    __syncthreads();
    f16* dst = (t == 0) ? quh : (t == 1) ? kuh : (t == 2) ? vuh : (t == 3) ? qch : kch;
    const int hb = (tf & 1023) >> 6;
#pragma unroll
    for (int q = 0; q < 8; ++q) {
      const int idx = q * 256 + tid, row = idx >> 4, c = idx & 15;
      const int h = hb + (c >> 3), d0 = (c & 7) * 8, n = tm + row;
      *(half8*)(dst + ((size_t)h * N + n) * DH + d0) = *(const half8*)(lds + row * LDSH + c * 8);
    }
  }
}

// Per pair (a<=b): sig tile PU(a,b) = triu1(sigmoid(qu[a].ku[b]^T)), computed ONCE;
// fused D-contribution D^{(b)}[a-rows] = sigtile @ vu[b-block]; for a==b also the
// diagonal term1 tile tril(qc[a].vu[a]^T). Grid (Gr,136): blockIdx.x = head (XCD pin).
__global__ __launch_bounds__(256) void k_dsig(const f16* __restrict__ quh, const f16* __restrict__ kuh,
                                              const f16* __restrict__ qch, const f16* __restrict__ vuh,
                                              const f16* __restrict__ vuT,
                                              f16* __restrict__ sigb, f16* __restrict__ DC,
                                              f16* __restrict__ diagb, int h0) {
  __shared__ __align__(16) f16 L[32768];  // quA 8192 | kuB 8192 (reused vtB0/vtB1) | s1 8192 | s2 8192
  f16* quA = L; f16* kuB = L + 8192; f16* s1 = L + 16384; f16* s2 = L + 24576;
  int b, a;
  decode_pair(blockIdx.y, b, a);
  const int hl = blockIdx.x, h = h0 + hl;
  const int tid = threadIdx.x, w = tid >> 6, l = tid & 63;
  const int q = l >> 4, m = l & 15;
  const int wm = (w >> 1) * 64, wn = (w & 1) * 64;
  const size_t ho = (size_t)h * N * DH;

  stage64<128, 256>(quh + ho + (size_t)(a * 128) * DH, DH, quA, tid);
  stage64<128, 256>(kuh + ho + (size_t)(b * 128) * DH, DH, kuB, tid);
  __syncthreads();
  float4v acc[4][4] = {};
  gemm64(quA, kuB, wm, wn, l, acc);  // qu[a] . ku[b]^T
  __syncthreads();  // quA/kuB reads done
  stage64<64, 256>(vuT + (size_t)h * DH * N + b * 128, N, kuB, tid);
  stage64<64, 256>(vuT + (size_t)h * DH * N + b * 128 + 64, N, kuB + 4096, tid);
  // sigmoid + strict-upper mask -> swizzled A-frag panels s1/s2
#pragma unroll
  for (int mi = 0; mi < 4; ++mi)
#pragma unroll
    for (int ni = 0; ni < 4; ++ni)
#pragma unroll
      for (int r = 0; r < 4; ++r) {
        const int row = wm + mi * 16 + q * 4 + r;   // k-local
        const int col = wn + ni * 16 + m;           // j-local
        const float x = acc[mi][ni][r];
        const f16 sv = (b * 128 + col > a * 128 + row) ? (f16)(1.f / (1.f + __expf(-x))) : (f16)0.f;
        wfrag((col < 64) ? s1 : s2, row, col & 63, sv);
      }
  __syncthreads();  // panels visible; vtB staged
  {
    f16* Sg = sigb + ((size_t)hl * NTILES + PU(a, b)) * TS;
#pragma unroll
    for (int qq = 0; qq < 8; ++qq) {
      const int idx = qq * 256 + tid, row = idx >> 4, c = idx & 15;
      const f16* p = ((c >> 3) ? s2 : s1) + row * 64 + (((c & 7) ^ (row & 7)) << 3);
      *(half8*)(Sg + (size_t)row * 128 + c * 8) = *(const half8*)p;
    }
  }
  float4v dacc[2][4] = {};
#pragma unroll
  for (int p = 0; p < 2; ++p)
#pragma unroll
    for (int ks = 0; ks < 2; ++ks) {
      half8 bf[4], af[2];
#pragma unroll
      for (int ni = 0; ni < 4; ++ni) bf[ni] = rdfrag(kuB + p * 4096, ni * 16 + m, ks, q);
#pragma unroll
      for (int mi = 0; mi < 2; ++mi) af[mi] = rdfrag(p ? s2 : s1, w * 32 + mi * 16 + m, ks, q);
#pragma unroll
      for (int mi = 0; mi < 2; ++mi)
#pragma unroll
        for (int ni = 0; ni < 4; ++ni)
          dacc[mi][ni] = __builtin_amdgcn_mfma_f32_16x16x32_f16(af[mi], bf[ni], dacc[mi][ni], 0, 0, 0);
    }
  __syncthreads();
  if (a == b) {
    stage64<128, 256>(qch + ho + (size_t)(a * 128) * DH, DH, quA, tid);
    stage64<128, 256>(vuh + ho + (size_t)(a * 128) * DH, DH, kuB, tid);
  }
  {
    f16* epsD = s1;
#pragma unroll
    for (int mi = 0; mi < 2; ++mi)
#pragma unroll
      for (int ni = 0; ni < 4; ++ni)
#pragma unroll
        for (int r = 0; r < 4; ++r)
          epsD[(w * 32 + mi * 16 + q * 4 + r) * 68 + ni * 16 + m] = (f16)dacc[mi][ni][r];
    __syncthreads();
    f16* Dg = DC + ((size_t)hl * 16 + b) * KD + (size_t)(a * 128) * 64;
#pragma unroll
    for (int qq = 0; qq < 4; ++qq) {
      const int idx = qq * 256 + tid, row = idx >> 3, c = idx & 7;
      *(half8*)(Dg + (size_t)row * 64 + c * 8) = *(const half8*)(epsD + row * 68 + c * 8);
    }
  }
  if (a == b) {
    float4v tacc[4][4] = {};
    gemm64(quA, kuB, wm, wn, l, tacc);  // qc[a] . vu[a]^T
    f16* Tg = diagb + ((size_t)hl * 16 + a) * TS;
#pragma unroll
    for (int mi = 0; mi < 4; ++mi)
#pragma unroll
      for (int ni = 0; ni < 4; ++ni)
#pragma unroll
        for (int r = 0; r < 4; ++r) {
          const int row = wm + mi * 16 + q * 4 + r, col = wn + ni * 16 + m;
          Tg[(size_t)row * 128 + col] = (col <= row) ? (f16)tacc[mi][ni][r] : (f16)0.f;
        }
  }
}

// In-place exclusive prefix over T: C^{(T)} = sum_{T'<T} D^{(T')}, f32 accumulate.
__global__ __launch_bounds__(256) void k_scan(f16* __restrict__ DC, int total) {
  const int idx = blockIdx.x * 256 + threadIdx.x;
  if (idx >= total) return;
  const int g = idx >> 17, off = idx & (KD - 1);
  const int a = off >> 13;
  f16* p = DC + (size_t)g * 16 * KD + off;
  float s = 0.f;
#pragma unroll
  for (int T = 0; T < 16; ++T) {
    const float v = (T >= a) ? (float)p[(size_t)T * KD] : 0.f;
    p[(size_t)T * KD] = (f16)s;
    s += v;
  }
}

// Fused scores + online-softmax + PV. Block = (head hl = blockIdx.x [XCD pin],
// 16-row tile rt). ROW-SPLIT vs previous version: 16-row tiles double the block
// count to (Gr,128) = 1024 blocks -> 4 blocks/CU resident (was grid-limited at 2),
// and halved register state lets __launch_bounds__(256,4) cap VGPR<=128 for
// 4 waves/SIMD of latency hiding. Rows are independent -> no new merge needed.
// 4 waves split 64-col jt-chunks (disjoint work -> register-direct B-frag loads;
// no LDS staging, no barriers in the main loop).
__global__ __launch_bounds__(256, 4) void k_favs(const f16* __restrict__ qch, const f16* __restrict__ kch,
                                                 const f16* __restrict__ DC, const f16* __restrict__ sigb,
                                                 const f16* __restrict__ diagb, const f16* __restrict__ vcT,
                                                 f16* __restrict__ Oh, int h0) {
  __shared__ float mlds[4][16], llds[4][16];
  __shared__ __align__(16) float olds[16][68];
  __shared__ __align__(16) f16 plds[4][16 * 64];
  const int hl = blockIdx.x, h = h0 + hl;
  const int rt = 127 - (int)blockIdx.y;  // longest-first, 16-row tiles
  const int tid = threadIdx.x, w = tid >> 6, l = tid & 63;
  const int q = l >> 4, m = l & 15;
  const int ti = rt >> 3, r0 = rt * 16;
  const size_t ho = (size_t)h * N * DH;
  const f16* qc = qch + ho;
  const f16* kc = kch + ho;
  const f16* Cb = DC + ((size_t)hl * 16 + ti) * KD;
  const f16* Td = diagb + ((size_t)hl * 16 + ti) * TS;
  const f16* Sgb = sigb + (size_t)hl * NTILES * TS;
  const f16* V = vcT + (size_t)h * DH * N;
  f16* pw = plds[w];

  // cached A-frags: qc rows [r0,r0+16) and T1diag rows (local) [dr,dr+16) x 128 j
  half8 qcA[2], tdA[4];
  const int dr = (rt & 7) * 16;
#pragma unroll
  for (int ks = 0; ks < 2; ++ks)
    qcA[ks] = *(const half8*)(qc + (size_t)(r0 + m) * DH + ks * 32 + q * 8);
#pragma unroll
  for (int ks = 0; ks < 4; ++ks)
    tdA[ks] = *(const half8*)(Td + (size_t)(dr + m) * 128 + ks * 32 + q * 8);

  float4v o[4] = {};
  float mrun[4], lrun[4];
#pragma unroll
  for (int r = 0; r < 4; ++r) { mrun[r] = -1e30f; lrun[r] = 0.f; }

  const int jtmax = rt >> 2;
  for (int jt = w; jt <= jtmax; jt += 4) {
    const int k0 = jt * 64;
    const int tkt = jt >> 1, koff = (jt & 1) * 64;
    const f16* Sg = Sgb + (size_t)PU(tkt, ti) * TS;
    float4v s[4] = {};
    // phase 1: qc . C^{(ti)}[k]^T  (K=64)
#pragma unroll
    for (int ks = 0; ks < 2; ++ks) {
      half8 bf[4];
#pragma unroll
      for (int ni = 0; ni < 4; ++ni)
        bf[ni] = *(const half8*)(Cb + (size_t)(k0 + ni * 16 + m) * 64 + ks * 32 + q * 8);
#pragma unroll
      for (int ni = 0; ni < 4; ++ni)
        s[ni] = __builtin_amdgcn_mfma_f32_16x16x32_f16(qcA[ks], bf[ni], s[ni], 0, 0, 0);
    }
    // phase 2: + T1diag . sig^T  (K=128)
#pragma unroll
    for (int ks = 0; ks < 4; ++ks) {
      half8 bf[4];
#pragma unroll
      for (int ni = 0; ni < 4; ++ni)
        bf[ni] = *(const half8*)(Sg + (size_t)(koff + ni * 16 + m) * 128 + ks * 32 + q * 8);
#pragma unroll
      for (int ni = 0; ni < 4; ++ni)
        s[ni] = __builtin_amdgcn_mfma_f32_16x16x32_f16(tdA[ks], bf[ni], s[ni], 0, 0, 0);
    }
    // s := -silu(Su)
#pragma unroll
    for (int ni = 0; ni < 4; ++ni)
#pragma unroll
      for (int r = 0; r < 4; ++r) {
        const float x = s[ni][r];
        s[ni][r] = -(x / (1.f + __expf(-x)));
      }
    // phase 3: + Sc = qc . kc^T  (K=64)
#pragma unroll
    for (int ks = 0; ks < 2; ++ks) {
      half8 bf[4];
#pragma unroll
      for (int ni = 0; ni < 4; ++ni)
        bf[ni] = *(const half8*)(kc + (size_t)(k0 + ni * 16 + m) * DH + ks * 32 + q * 8);
#pragma unroll
      for (int ni = 0; ni < 4; ++ni)
        s[ni] = __builtin_amdgcn_mfma_f32_16x16x32_f16(qcA[ks], bf[ni], s[ni], 0, 0, 0);
    }
    // causal mask (only the diagonal chunk has cols > some rows)
    if (jt == jtmax) {
#pragma unroll
      for (int ni = 0; ni < 4; ++ni) {
        const int col = k0 + ni * 16 + m;
#pragma unroll
        for (int r = 0; r < 4; ++r)
          if (col > r0 + q * 4 + r) s[ni][r] = -1e30f;
      }
    }
    // online softmax (C-layout: rows = q*4 + r)
    float al[4], ts[4];
#pragma unroll
    for (int r = 0; r < 4; ++r) {
      float tmx = fmaxf(fmaxf(s[0][r], s[1][r]), fmaxf(s[2][r], s[3][r]));
#pragma unroll
      for (int x = 1; x < 16; x <<= 1) tmx = fmaxf(tmx, __shfl_xor(tmx, x));
      const float nm = fmaxf(mrun[r], tmx);
      al[r] = __expf(mrun[r] - nm);
      mrun[r] = nm;
      ts[r] = 0.f;
    }
#pragma unroll
    for (int ni = 0; ni < 4; ++ni)
#pragma unroll
      for (int r = 0; r < 4; ++r) {
        const float p = __expf(s[ni][r] - mrun[r]);
        wfrag(pw, q * 4 + r, ni * 16 + m, (f16)p);
        ts[r] += p;
      }
#pragma unroll
    for (int r = 0; r < 4; ++r) {
#pragma unroll
      for (int x = 1; x < 16; x <<= 1) ts[r] += __shfl_xor(ts[r], x);
      lrun[r] = lrun[r] * al[r] + ts[r];
#pragma unroll
      for (int ni = 0; ni < 4; ++ni) o[ni][r] *= al[r];
    }
    // PV: O += P(A-layout via LDS) . vc(B from vcT)
#pragma unroll
    for (int ks = 0; ks < 2; ++ks) {
      half8 af, bf[4];
      af = rdfrag(pw, m, ks, q);
#pragma unroll
      for (int ni = 0; ni < 4; ++ni)
        bf[ni] = *(const half8*)(V + (size_t)(ni * 16 + m) * N + k0 + ks * 32 + q * 8);
#pragma unroll
      for (int ni = 0; ni < 4; ++ni)
        o[ni] = __builtin_amdgcn_mfma_f32_16x16x32_f16(af, bf[ni], o[ni], 0, 0, 0);
    }
  }
  // merge the 4 waves
  if (m == 0)
#pragma unroll
    for (int r = 0; r < 4; ++r) {
      mlds[w][q * 4 + r] = mrun[r];
      llds[w][q * 4 + r] = lrun[r];
    }
  __syncthreads();
#pragma unroll
  for (int r = 0; r < 4; ++r) {
    const int row = q * 4 + r;
    const float mstar = fmaxf(fmaxf(mlds[0][row], mlds[1][row]), fmaxf(mlds[2][row], mlds[3][row]));
    const float sw = __expf(mlds[w][row] - mstar);
#pragma unroll
    for (int ni = 0; ni < 4; ++ni) o[ni][r] *= sw;
  }
#pragma unroll
  for (int t = 0; t < 4; ++t) {
    if (w == t) {
#pragma unroll
      for (int ni = 0; ni < 4; ++ni)
#pragma unroll
        for (int r = 0; r < 4; ++r) {
          const int row = q * 4 + r, col = ni * 16 + m;
          if (t == 0) olds[row][col] = o[ni][r];
          else olds[row][col] += o[ni][r];
        }
    }
    __syncthreads();
  }
  if (tid < 128) {
    const int row = tid >> 3, c = tid & 7;
    const float mstar = fmaxf(fmaxf(mlds[0][row], mlds[1][row]), fmaxf(mlds[2][row], mlds[3][row]));
    float denom = 0.f;
#pragma unroll
    for (int t = 0; t < 4; ++t) denom += __expf(mlds[t][row] - mstar) * llds[t][row];
    const float inv = 1.f / denom;
    half8 o8;
#pragma unroll
    for (int e = 0; e < 8; ++e) o8[e] = (f16)(olds[row][c * 8 + e] * inv);
    *(half8*)(Oh + (size_t)(r0 + row) * (H * DH) + h * DH + c * 8) = o8;
  }
}

// out = O @ w_out^T, fp32 result.
__global__ __launch_bounds__(256) void k_out(const f16* __restrict__ Oh, const f16* __restrict__ wo,
                                             float* __restrict__ out) {
  __shared__ __align__(16) f16 lds[128 * LDSH];
  f16* As = lds; f16* Bs = lds + 128 * 64;
  const int tid = threadIdx.x, w = tid >> 6, l = tid & 63;
  const int tm = blockIdx.x * 128, tn = blockIdx.y * 128;
  const int wm = (w >> 1) * 64, wn = (w & 1) * 64;
  float4v acc[4][4] = {};
  for (int k0 = 0; k0 < DIM; k0 += 64) {
    stage64<128, 256>(Oh + (size_t)tm * DIM + k0, DIM, As, tid);
    stage64<128, 256>(wo + (size_t)tn * DIM + k0, DIM, Bs, tid);
    __syncthreads();
    gemm64(As, Bs, wm, wn, l, acc);
    __syncthreads();
  }
  const int rbase = (l >> 4) * 4, cidx = l & 15;
#pragma unroll
  for (int mi = 0; mi < 4; ++mi)
#pragma unroll
    for (int ni = 0; ni < 4; ++ni)
#pragma unroll
      for (int r = 0; r < 4; ++r) {
        const int n = tm + wm + mi * 16 + rbase + r;
        const int dmo = tn + wn + ni * 16 + cidx;
        out[(size_t)n * DIM + dmo] = acc[mi][ni][r];
      }
}

extern "C" void kernel_launch(void* const* d_in, const int* in_sizes, int n_in,
                              void* d_out, int out_size, void* d_ws, size_t ws_size,
                              hipStream_t stream) {
  const float* x = (const float*)d_in[0];
  const float* wqkv = (const float*)d_in[1];
  const float* wout = (const float*)d_in[2];
  float* out = (float*)d_out;
  char* ws = (char*)d_ws;

  size_t off = 0;
  auto alloc = [&](size_t b) { size_t o = off; off += (b + 255) & ~(size_t)255; return o; };
  f16* xh  = (f16*)(ws + alloc((size_t)N * DIM * 2));
  f16* wqh = (f16*)(ws + alloc((size_t)F6 * DIM * 2));
  f16* woh = (f16*)(ws + alloc((size_t)DIM * H * DH * 2));
  f16* quh = (f16*)(ws + alloc((size_t)H * N * DH * 2));
  f16* kuh = (f16*)(ws + alloc((size_t)H * N * DH * 2));
  f16* vuh = (f16*)(ws + alloc((size_t)H * N * DH * 2));
  f16* qch = (f16*)(ws + alloc((size_t)H * N * DH * 2));
  f16* kch = (f16*)(ws + alloc((size_t)H * N * DH * 2));
  f16* vcT = (f16*)(ws + alloc((size_t)H * DH * N * 2));
  f16* vuT = (f16*)(ws + alloc((size_t)H * DH * N * 2));
  f16* Oh  = (f16*)(ws + alloc((size_t)N * H * DH * 2));
  const size_t persist = off;

  // per head: sig tiles + D/C + diag tiles (scob eliminated by k_favs fusion)
  const size_t per_head = ((size_t)NTILES * TS + (size_t)16 * KD + (size_t)16 * TS) * 2;
  int G = (ws_size > persist + 4096) ? (int)((ws_size - persist - 4096) / per_head) : 1;
  if (G < 1) G = 1;
  if (G > 16) G = 16;
  {  // normalize so rounds are evenly sized (prefer G=8 for head->XCD pinning)
    const int R = (H + G - 1) / G;
    G = (H + R - 1) / R;
  }
  f16* sigb  = (f16*)(ws + alloc((size_t)G * NTILES * TS * 2));
  f16* DC    = (f16*)(ws + alloc((size_t)G * 16 * KD * 2));
  f16* diagb = (f16*)(ws + alloc((size_t)G * 16 * TS * 2));

  k_cast<<<(N * DIM / 4 + 255) / 256, 256, 0, stream>>>(x, xh, N * DIM / 4);
  k_cast<<<(F6 * DIM / 4 + 255) / 256, 256, 0, stream>>>(wqkv, wqh, F6 * DIM / 4);
  k_cast<<<(DIM * H * DH / 4 + 255) / 256, 256, 0, stream>>>(wout, woh, DIM * H * DH / 4);

  k_qkv<<<dim3(N / 128, F6 / 128), 256, 0, stream>>>(xh, wqh, quh, kuh, vuh, qch, kch, vcT, vuT);

  for (int h0 = 0; h0 < H; h0 += G) {
    const int Gr = (H - h0 < G) ? (H - h0) : G;
    k_dsig<<<dim3(Gr, 136), 256, 0, stream>>>(quh, kuh, qch, vuh, vuT, sigb, DC, diagb, h0);
    k_scan<<<(Gr * KD + 255) / 256, 256, 0, stream>>>(DC, Gr * KD);
    k_favs<<<dim3(Gr, 128), 256, 0, stream>>>(qch, kch, DC, sigb, diagb, vcT, Oh, h0);
  }

  k_out<<<dim3(16, 8), 256, 0, stream>>>(Oh, woh, out);
}

// Round 2
// 375.085 us; speedup vs baseline: 1.0617x; 1.0617x over previous
//
#include <hip/hip_runtime.h>

using f16 = _Float16;
using half8  = __attribute__((ext_vector_type(8))) f16;
using half4v = __attribute__((ext_vector_type(4))) f16;
using float4v = __attribute__((ext_vector_type(4))) float;

#define DEV static __device__ __forceinline__

constexpr int N = 2048, DIM = 1024, H = 16, DH = 64, F6 = 6144;
constexpr int LDSH = 136;       // f16 epilogue row stride (halves)
constexpr int TS = 128 * 128;   // packed tile elements
constexpr int NTILES = 136;     // triangular 128x128 tiles per head
constexpr int KD = 2048 * 64;   // D/C elements per T-slice per head

DEV int PL(int i, int k) { return i * (i + 1) / 2 + k; }                  // lower, k<=i
DEV int PU(int a, int b) { return a * 16 - a * (a - 1) / 2 + (b - a); }   // upper, a<=b

template<int ROWS, int THREADS>
DEV void stage64(const f16* __restrict__ g, int strideHalves, f16* lds, int tid) {
#pragma unroll
  for (int q = 0; q < (ROWS * 8) / THREADS; ++q) {
    const int chunk = q * THREADS + tid;
    const int m = chunk >> 3, c = (chunk & 7) ^ (m & 7);
    const f16* gp = g + (size_t)m * strideHalves + c * 8;
    __builtin_amdgcn_global_load_lds(
        (const __attribute__((address_space(1))) unsigned int*)gp,
        (__attribute__((address_space(3))) unsigned int*)(lds + chunk * 8), 16, 0, 0);
  }
}

DEV half8 rdfrag(const f16* T, int m, int ks, int q) {
  const int c = (ks * 4 + q) ^ (m & 7);
  return *(const half8*)(T + m * 64 + c * 8);
}

// store one element into frag layout (inverse of rdfrag addressing)
DEV void wfrag(f16* T, int row, int col, f16 v) {
  T[row * 64 + ((((col >> 3) ^ (row & 7)) << 3) | (col & 7))] = v;
}

DEV void gemm64(const f16* As, const f16* Bs, int wm, int wn, int l, float4v acc[4][4]) {
  const int q = l >> 4, mm = l & 15;
#pragma unroll
  for (int ks = 0; ks < 2; ++ks) {
    half8 af[4], bf[4];
#pragma unroll
    for (int mi = 0; mi < 4; ++mi) af[mi] = rdfrag(As, wm + mm + mi * 16, ks, q);
#pragma unroll
    for (int ni = 0; ni < 4; ++ni) bf[ni] = rdfrag(Bs, wn + mm + ni * 16, ks, q);
#pragma unroll
    for (int mi = 0; mi < 4; ++mi)
#pragma unroll
      for (int ni = 0; ni < 4; ++ni)
        acc[mi][ni] = __builtin_amdgcn_mfma_f32_16x16x32_f16(af[mi], bf[ni], acc[mi][ni], 0, 0, 0);
  }
}

// p in [0,136) -> (ti,tk), tk<=ti.
DEV void decode_pair(int p, int& ti, int& tk) {
  int t = (int)((sqrtf(8.f * p + 1.f) - 1.f) * 0.5f);
  while (t * (t + 1) / 2 > p) --t;
  while ((t + 1) * (t + 2) / 2 <= p) ++t;
  const int i2 = p - t * (t + 1) / 2;
  ti = (15 - t) + i2;
  tk = i2;
}

__global__ __launch_bounds__(256) void k_cast(const float* __restrict__ s, f16* __restrict__ d, int n4) {
  int i = blockIdx.x * 256 + threadIdx.x;
  if (i < n4) {
    float4 v = ((const float4*)s)[i];
    half4v h;
    h[0] = (f16)v.x; h[1] = (f16)v.y; h[2] = (f16)v.z; h[3] = (f16)v.w;
    ((half4v*)d)[i] = h;
  }
}

// qkvs = x @ w_qkv^T; per-head scatter. vu additionally stored transposed (vuT[h][d][n]).
__global__ __launch_bounds__(256) void k_qkv(const f16* __restrict__ xh, const f16* __restrict__ wh,
                                             f16* __restrict__ quh, f16* __restrict__ kuh,
                                             f16* __restrict__ vuh, f16* __restrict__ qch,
                                             f16* __restrict__ kch, f16* __restrict__ vcT,
                                             f16* __restrict__ vuT) {
  __shared__ __align__(16) f16 lds[128 * LDSH];
  f16* As = lds; f16* Bs = lds + 128 * 64;
  const int tid = threadIdx.x, w = tid >> 6, l = tid & 63;
  const int tm = blockIdx.x * 128, tf = blockIdx.y * 128;
  const int wm = (w >> 1) * 64, wn = (w & 1) * 64;
  float4v acc[4][4] = {};
  for (int k0 = 0; k0 < DIM; k0 += 64) {
    stage64<128, 256>(xh + (size_t)tm * DIM + k0, DIM, As, tid);
    stage64<128, 256>(wh + (size_t)tf * DIM + k0, DIM, Bs, tid);
    __syncthreads();
    gemm64(As, Bs, wm, wn, l, acc);
    __syncthreads();
  }
  const int rbase = (l >> 4) * 4, cidx = l & 15;
  const int t = tf >> 10;
  const float sc = (t == 0 || t == 3) ? 0.125f : 1.f;
  if (t == 5 || t == 2) {
    f16* T = (t == 5) ? vcT : vuT;
#pragma unroll
    for (int mi = 0; mi < 4; ++mi)
#pragma unroll
      for (int ni = 0; ni < 4; ++ni) {
        const int f = tf + wn + ni * 16 + cidx;
        const int h = (f & 1023) >> 6, d = f & 63;
        half4v p;
#pragma unroll
        for (int r = 0; r < 4; ++r) p[r] = (f16)acc[mi][ni][r];
        *(half4v*)(T + ((size_t)h * DH + d) * N + (tm + wm + mi * 16 + rbase)) = p;
      }
  }
  if (t != 5) {
#pragma unroll
    for (int mi = 0; mi < 4; ++mi)
#pragma unroll
      for (int ni = 0; ni < 4; ++ni)
#pragma unroll
        for (int r = 0; r < 4; ++r)
          lds[(wm + mi * 16 + rbase + r) * LDSH + wn + ni * 16 + cidx] = (f16)(acc[mi][ni][r] * sc);
    __syncthreads();
    f16* dst = (t == 0) ? quh : (t == 1) ? kuh : (t == 2) ? vuh : (t == 3) ? qch : kch;
    const int hb = (tf & 1023) >> 6;
#pragma unroll
    for (int q = 0; q < 8; ++q) {
      const int idx = q * 256 + tid, row = idx >> 4, c = idx & 15;
      const int h = hb + (c >> 3), d0 = (c & 7) * 8, n = tm + row;
      *(half8*)(dst + ((size_t)h * N + n) * DH + d0) = *(const half8*)(lds + row * LDSH + c * 8);
    }
  }
}

// Per pair (a<=b): sig tile PU(a,b) = triu1(sigmoid(qu[a].ku[b]^T)), computed ONCE;
// fused D-contribution D^{(b)}[a-rows] = sigtile @ vu[b-block]; for a==b also the
// diagonal term1 tile tril(qc[a].vu[a]^T). Grid (Gr,136): blockIdx.x = head (XCD pin).
__global__ __launch_bounds__(256) void k_dsig(const f16* __restrict__ quh, const f16* __restrict__ kuh,
                                              const f16* __restrict__ qch, const f16* __restrict__ vuh,
                                              const f16* __restrict__ vuT,
                                              f16* __restrict__ sigb, f16* __restrict__ DC,
                                              f16* __restrict__ diagb, int h0) {
  __shared__ __align__(16) f16 L[32768];  // quA 8192 | kuB 8192 (reused vtB0/vtB1) | s1 8192 | s2 8192
  f16* quA = L; f16* kuB = L + 8192; f16* s1 = L + 16384; f16* s2 = L + 24576;
  int b, a;
  decode_pair(blockIdx.y, b, a);
  const int hl = blockIdx.x, h = h0 + hl;
  const int tid = threadIdx.x, w = tid >> 6, l = tid & 63;
  const int q = l >> 4, m = l & 15;
  const int wm = (w >> 1) * 64, wn = (w & 1) * 64;
  const size_t ho = (size_t)h * N * DH;

  stage64<128, 256>(quh + ho + (size_t)(a * 128) * DH, DH, quA, tid);
  stage64<128, 256>(kuh + ho + (size_t)(b * 128) * DH, DH, kuB, tid);
  __syncthreads();
  float4v acc[4][4] = {};
  gemm64(quA, kuB, wm, wn, l, acc);  // qu[a] . ku[b]^T
  __syncthreads();  // quA/kuB reads done
  stage64<64, 256>(vuT + (size_t)h * DH * N + b * 128, N, kuB, tid);
  stage64<64, 256>(vuT + (size_t)h * DH * N + b * 128 + 64, N, kuB + 4096, tid);
  // sigmoid + strict-upper mask -> swizzled A-frag panels s1/s2
#pragma unroll
  for (int mi = 0; mi < 4; ++mi)
#pragma unroll
    for (int ni = 0; ni < 4; ++ni)
#pragma unroll
      for (int r = 0; r < 4; ++r) {
        const int row = wm + mi * 16 + q * 4 + r;   // k-local
        const int col = wn + ni * 16 + m;           // j-local
        const float x = acc[mi][ni][r];
        const f16 sv = (b * 128 + col > a * 128 + row) ? (f16)(1.f / (1.f + __expf(-x))) : (f16)0.f;
        wfrag((col < 64) ? s1 : s2, row, col & 63, sv);
      }
  __syncthreads();  // panels visible; vtB staged
  {
    f16* Sg = sigb + ((size_t)hl * NTILES + PU(a, b)) * TS;
#pragma unroll
    for (int qq = 0; qq < 8; ++qq) {
      const int idx = qq * 256 + tid, row = idx >> 4, c = idx & 15;
      const f16* p = ((c >> 3) ? s2 : s1) + row * 64 + (((c & 7) ^ (row & 7)) << 3);
      *(half8*)(Sg + (size_t)row * 128 + c * 8) = *(const half8*)p;
    }
  }
  float4v dacc[2][4] = {};
#pragma unroll
  for (int p = 0; p < 2; ++p)
#pragma unroll
    for (int ks = 0; ks < 2; ++ks) {
      half8 bf[4], af[2];
#pragma unroll
      for (int ni = 0; ni < 4; ++ni) bf[ni] = rdfrag(kuB + p * 4096, ni * 16 + m, ks, q);
#pragma unroll
      for (int mi = 0; mi < 2; ++mi) af[mi] = rdfrag(p ? s2 : s1, w * 32 + mi * 16 + m, ks, q);
#pragma unroll
      for (int mi = 0; mi < 2; ++mi)
#pragma unroll
        for (int ni = 0; ni < 4; ++ni)
          dacc[mi][ni] = __builtin_amdgcn_mfma_f32_16x16x32_f16(af[mi], bf[ni], dacc[mi][ni], 0, 0, 0);
    }
  __syncthreads();
  if (a == b) {
    stage64<128, 256>(qch + ho + (size_t)(a * 128) * DH, DH, quA, tid);
    stage64<128, 256>(vuh + ho + (size_t)(a * 128) * DH, DH, kuB, tid);
  }
  {
    f16* epsD = s1;
#pragma unroll
    for (int mi = 0; mi < 2; ++mi)
#pragma unroll
      for (int ni = 0; ni < 4; ++ni)
#pragma unroll
        for (int r = 0; r < 4; ++r)
          epsD[(w * 32 + mi * 16 + q * 4 + r) * 68 + ni * 16 + m] = (f16)dacc[mi][ni][r];
    __syncthreads();
    f16* Dg = DC + ((size_t)hl * 16 + b) * KD + (size_t)(a * 128) * 64;
#pragma unroll
    for (int qq = 0; qq < 4; ++qq) {
      const int idx = qq * 256 + tid, row = idx >> 3, c = idx & 7;
      *(half8*)(Dg + (size_t)row * 64 + c * 8) = *(const half8*)(epsD + row * 68 + c * 8);
    }
  }
  if (a == b) {
    float4v tacc[4][4] = {};
    gemm64(quA, kuB, wm, wn, l, tacc);  // qc[a] . vu[a]^T
    f16* Tg = diagb + ((size_t)hl * 16 + a) * TS;
#pragma unroll
    for (int mi = 0; mi < 4; ++mi)
#pragma unroll
      for (int ni = 0; ni < 4; ++ni)
#pragma unroll
        for (int r = 0; r < 4; ++r) {
          const int row = wm + mi * 16 + q * 4 + r, col = wn + ni * 16 + m;
          Tg[(size_t)row * 128 + col] = (col <= row) ? (f16)tacc[mi][ni][r] : (f16)0.f;
        }
  }
}

// In-place exclusive prefix over T: C^{(T)} = sum_{T'<T} D^{(T')}, f32 accumulate.
__global__ __launch_bounds__(256) void k_scan(f16* __restrict__ DC, int total) {
  const int idx = blockIdx.x * 256 + threadIdx.x;
  if (idx >= total) return;
  const int g = idx >> 17, off = idx & (KD - 1);
  const int a = off >> 13;
  f16* p = DC + (size_t)g * 16 * KD + off;
  float s = 0.f;
#pragma unroll
  for (int T = 0; T < 16; ++T) {
    const float v = (T >= a) ? (float)p[(size_t)T * KD] : 0.f;
    p[(size_t)T * KD] = (f16)s;
    s += v;
  }
}

// Fused scores + online-softmax + PV. Block = (head hl = blockIdx.x [XCD pin],
// 16-row tile rt). 16-row tiles -> (Gr,128) = 1024 blocks = 4 blocks/CU resident.
// __launch_bounds__(256,3): VGPR cap ~168 -> NO spills (round-1's (256,4) capped
// at 64 and spilled ~150 MB of scratch traffic); natural allocation ~110-120 still
// yields 4 blocks/CU. Zigzag y->rt mapping: co-resident blocks {y, y+32, y+64, y+96}
// (round-robin dispatch) get rt summing to a constant 254 -> per-CU work balanced.
// 4 waves split 64-col jt-chunks (disjoint work -> register-direct B-frag loads;
// no LDS staging, no barriers in the main loop).
__global__ __launch_bounds__(256, 3) void k_favs(const f16* __restrict__ qch, const f16* __restrict__ kch,
                                                 const f16* __restrict__ DC, const f16* __restrict__ sigb,
                                                 const f16* __restrict__ diagb, const f16* __restrict__ vcT,
                                                 f16* __restrict__ Oh, int h0) {
  __shared__ float mlds[4][16], llds[4][16];
  __shared__ __align__(16) float olds[16][68];
  __shared__ __align__(16) f16 plds[4][16 * 64];
  const int hl = blockIdx.x, h = h0 + hl;
  const int y = (int)blockIdx.y;
  const int aq = y >> 5, kq = y & 31;
  const int rt = (aq & 1) ? (aq * 32 + 31 - kq) : (aq * 32 + kq);  // zigzag balance
  const int tid = threadIdx.x, w = tid >> 6, l = tid & 63;
  const int q = l >> 4, m = l & 15;
  const int ti = rt >> 3, r0 = rt * 16;
  const size_t ho = (size_t)h * N * DH;
  const f16* qc = qch + ho;
  const f16* kc = kch + ho;
  const f16* Cb = DC + ((size_t)hl * 16 + ti) * KD;
  const f16* Td = diagb + ((size_t)hl * 16 + ti) * TS;
  const f16* Sgb = sigb + (size_t)hl * NTILES * TS;
  const f16* V = vcT + (size_t)h * DH * N;
  f16* pw = plds[w];

  // cached A-frags: qc rows [r0,r0+16) and T1diag rows (local) [dr,dr+16) x 128 j
  half8 qcA[2], tdA[4];
  const int dr = (rt & 7) * 16;
#pragma unroll
  for (int ks = 0; ks < 2; ++ks)
    qcA[ks] = *(const half8*)(qc + (size_t)(r0 + m) * DH + ks * 32 + q * 8);
#pragma unroll
  for (int ks = 0; ks < 4; ++ks)
    tdA[ks] = *(const half8*)(Td + (size_t)(dr + m) * 128 + ks * 32 + q * 8);

  float4v o[4] = {};
  float mrun[4], lrun[4];
#pragma unroll
  for (int r = 0; r < 4; ++r) { mrun[r] = -1e30f; lrun[r] = 0.f; }

  const int jtmax = rt >> 2;
  for (int jt = w; jt <= jtmax; jt += 4) {
    const int k0 = jt * 64;
    const int tkt = jt >> 1, koff = (jt & 1) * 64;
    const f16* Sg = Sgb + (size_t)PU(tkt, ti) * TS;
    float4v s[4] = {};
    // phase 1: qc . C^{(ti)}[k]^T  (K=64)
#pragma unroll
    for (int ks = 0; ks < 2; ++ks) {
      half8 bf[4];
#pragma unroll
      for (int ni = 0; ni < 4; ++ni)
        bf[ni] = *(const half8*)(Cb + (size_t)(k0 + ni * 16 + m) * 64 + ks * 32 + q * 8);
#pragma unroll
      for (int ni = 0; ni < 4; ++ni)
        s[ni] = __builtin_amdgcn_mfma_f32_16x16x32_f16(qcA[ks], bf[ni], s[ni], 0, 0, 0);
    }
    // phase 2: + T1diag . sig^T  (K=128)
#pragma unroll
    for (int ks = 0; ks < 4; ++ks) {
      half8 bf[4];
#pragma unroll
      for (int ni = 0; ni < 4; ++ni)
        bf[ni] = *(const half8*)(Sg + (size_t)(koff + ni * 16 + m) * 128 + ks * 32 + q * 8);
#pragma unroll
      for (int ni = 0; ni < 4; ++ni)
        s[ni] = __builtin_amdgcn_mfma_f32_16x16x32_f16(tdA[ks], bf[ni], s[ni], 0, 0, 0);
    }
    // s := -silu(Su)
#pragma unroll
    for (int ni = 0; ni < 4; ++ni)
#pragma unroll
      for (int r = 0; r < 4; ++r) {
        const float x = s[ni][r];
        s[ni][r] = -(x / (1.f + __expf(-x)));
      }
    // phase 3: + Sc = qc . kc^T  (K=64)
#pragma unroll
    for (int ks = 0; ks < 2; ++ks) {
      half8 bf[4];
#pragma unroll
      for (int ni = 0; ni < 4; ++ni)
        bf[ni] = *(const half8*)(kc + (size_t)(k0 + ni * 16 + m) * DH + ks * 32 + q * 8);
#pragma unroll
      for (int ni = 0; ni < 4; ++ni)
        s[ni] = __builtin_amdgcn_mfma_f32_16x16x32_f16(qcA[ks], bf[ni], s[ni], 0, 0, 0);
    }
    // causal mask (only the diagonal chunk has cols > some rows)
    if (jt == jtmax) {
#pragma unroll
      for (int ni = 0; ni < 4; ++ni) {
        const int col = k0 + ni * 16 + m;
#pragma unroll
        for (int r = 0; r < 4; ++r)
          if (col > r0 + q * 4 + r) s[ni][r] = -1e30f;
      }
    }
    // online softmax (C-layout: rows = q*4 + r)
    float al[4], ts[4];
#pragma unroll
    for (int r = 0; r < 4; ++r) {
      float tmx = fmaxf(fmaxf(s[0][r], s[1][r]), fmaxf(s[2][r], s[3][r]));
#pragma unroll
      for (int x = 1; x < 16; x <<= 1) tmx = fmaxf(tmx, __shfl_xor(tmx, x));
      const float nm = fmaxf(mrun[r], tmx);
      al[r] = __expf(mrun[r] - nm);
      mrun[r] = nm;
      ts[r] = 0.f;
    }
#pragma unroll
    for (int ni = 0; ni < 4; ++ni)
#pragma unroll
      for (int r = 0; r < 4; ++r) {
        const float p = __expf(s[ni][r] - mrun[r]);
        wfrag(pw, q * 4 + r, ni * 16 + m, (f16)p);
        ts[r] += p;
      }
#pragma unroll
    for (int r = 0; r < 4; ++r) {
#pragma unroll
      for (int x = 1; x < 16; x <<= 1) ts[r] += __shfl_xor(ts[r], x);
      lrun[r] = lrun[r] * al[r] + ts[r];
#pragma unroll
      for (int ni = 0; ni < 4; ++ni) o[ni][r] *= al[r];
    }
    // PV: O += P(A-layout via LDS) . vc(B from vcT)
#pragma unroll
    for (int ks = 0; ks < 2; ++ks) {
      half8 af, bf[4];
      af = rdfrag(pw, m, ks, q);
#pragma unroll
      for (int ni = 0; ni < 4; ++ni)
        bf[ni] = *(const half8*)(V + (size_t)(ni * 16 + m) * N + k0 + ks * 32 + q * 8);
#pragma unroll
      for (int ni = 0; ni < 4; ++ni)
        o[ni] = __builtin_amdgcn_mfma_f32_16x16x32_f16(af, bf[ni], o[ni], 0, 0, 0);
    }
  }
  // merge the 4 waves
  if (m == 0)
#pragma unroll
    for (int r = 0; r < 4; ++r) {
      mlds[w][q * 4 + r] = mrun[r];
      llds[w][q * 4 + r] = lrun[r];
    }
  __syncthreads();
#pragma unroll
  for (int r = 0; r < 4; ++r) {
    const int row = q * 4 + r;
    const float mstar = fmaxf(fmaxf(mlds[0][row], mlds[1][row]), fmaxf(mlds[2][row], mlds[3][row]));
    const float sw = __expf(mlds[w][row] - mstar);
#pragma unroll
    for (int ni = 0; ni < 4; ++ni) o[ni][r] *= sw;
  }
#pragma unroll
  for (int t = 0; t < 4; ++t) {
    if (w == t) {
#pragma unroll
      for (int ni = 0; ni < 4; ++ni)
#pragma unroll
        for (int r = 0; r < 4; ++r) {
          const int row = q * 4 + r, col = ni * 16 + m;
          if (t == 0) olds[row][col] = o[ni][r];
          else olds[row][col] += o[ni][r];
        }
    }
    __syncthreads();
  }
  if (tid < 128) {
    const int row = tid >> 3, c = tid & 7;
    const float mstar = fmaxf(fmaxf(mlds[0][row], mlds[1][row]), fmaxf(mlds[2][row], mlds[3][row]));
    float denom = 0.f;
#pragma unroll
    for (int t = 0; t < 4; ++t) denom += __expf(mlds[t][row] - mstar) * llds[t][row];
    const float inv = 1.f / denom;
    half8 o8;
#pragma unroll
    for (int e = 0; e < 8; ++e) o8[e] = (f16)(olds[row][c * 8 + e] * inv);
    *(half8*)(Oh + (size_t)(r0 + row) * (H * DH) + h * DH + c * 8) = o8;
  }
}

// out = O @ w_out^T, fp32 result.
__global__ __launch_bounds__(256) void k_out(const f16* __restrict__ Oh, const f16* __restrict__ wo,
                                             float* __restrict__ out) {
  __shared__ __align__(16) f16 lds[128 * LDSH];
  f16* As = lds; f16* Bs = lds + 128 * 64;
  const int tid = threadIdx.x, w = tid >> 6, l = tid & 63;
  const int tm = blockIdx.x * 128, tn = blockIdx.y * 128;
  const int wm = (w >> 1) * 64, wn = (w & 1) * 64;
  float4v acc[4][4] = {};
  for (int k0 = 0; k0 < DIM; k0 += 64) {
    stage64<128, 256>(Oh + (size_t)tm * DIM + k0, DIM, As, tid);
    stage64<128, 256>(wo + (size_t)tn * DIM + k0, DIM, Bs, tid);
    __syncthreads();
    gemm64(As, Bs, wm, wn, l, acc);
    __syncthreads();
  }
  const int rbase = (l >> 4) * 4, cidx = l & 15;
#pragma unroll
  for (int mi = 0; mi < 4; ++mi)
#pragma unroll
    for (int ni = 0; ni < 4; ++ni)
#pragma unroll
      for (int r = 0; r < 4; ++r) {
        const int n = tm + wm + mi * 16 + rbase + r;
        const int dmo = tn + wn + ni * 16 + cidx;
        out[(size_t)n * DIM + dmo] = acc[mi][ni][r];
      }
}

extern "C" void kernel_launch(void* const* d_in, const int* in_sizes, int n_in,
                              void* d_out, int out_size, void* d_ws, size_t ws_size,
                              hipStream_t stream) {
  const float* x = (const float*)d_in[0];
  const float* wqkv = (const float*)d_in[1];
  const float* wout = (const float*)d_in[2];
  float* out = (float*)d_out;
  char* ws = (char*)d_ws;

  size_t off = 0;
  auto alloc = [&](size_t b) { size_t o = off; off += (b + 255) & ~(size_t)255; return o; };
  f16* xh  = (f16*)(ws + alloc((size_t)N * DIM * 2));
  f16* wqh = (f16*)(ws + alloc((size_t)F6 * DIM * 2));
  f16* woh = (f16*)(ws + alloc((size_t)DIM * H * DH * 2));
  f16* quh = (f16*)(ws + alloc((size_t)H * N * DH * 2));
  f16* kuh = (f16*)(ws + alloc((size_t)H * N * DH * 2));
  f16* vuh = (f16*)(ws + alloc((size_t)H * N * DH * 2));
  f16* qch = (f16*)(ws + alloc((size_t)H * N * DH * 2));
  f16* kch = (f16*)(ws + alloc((size_t)H * N * DH * 2));
  f16* vcT = (f16*)(ws + alloc((size_t)H * DH * N * 2));
  f16* vuT = (f16*)(ws + alloc((size_t)H * DH * N * 2));
  f16* Oh  = (f16*)(ws + alloc((size_t)N * H * DH * 2));
  const size_t persist = off;

  // per head: sig tiles + D/C + diag tiles (scob eliminated by k_favs fusion)
  const size_t per_head = ((size_t)NTILES * TS + (size_t)16 * KD + (size_t)16 * TS) * 2;
  int G = (ws_size > persist + 4096) ? (int)((ws_size - persist - 4096) / per_head) : 1;
  if (G < 1) G = 1;
  if (G > 16) G = 16;
  {  // normalize so rounds are evenly sized (prefer G=8 for head->XCD pinning)
    const int R = (H + G - 1) / G;
    G = (H + R - 1) / R;
  }
  f16* sigb  = (f16*)(ws + alloc((size_t)G * NTILES * TS * 2));
  f16* DC    = (f16*)(ws + alloc((size_t)G * 16 * KD * 2));
  f16* diagb = (f16*)(ws + alloc((size_t)G * 16 * TS * 2));

  k_cast<<<(N * DIM / 4 + 255) / 256, 256, 0, stream>>>(x, xh, N * DIM / 4);
  k_cast<<<(F6 * DIM / 4 + 255) / 256, 256, 0, stream>>>(wqkv, wqh, F6 * DIM / 4);
  k_cast<<<(DIM * H * DH / 4 + 255) / 256, 256, 0, stream>>>(wout, woh, DIM * H * DH / 4);

  k_qkv<<<dim3(N / 128, F6 / 128), 256, 0, stream>>>(xh, wqh, quh, kuh, vuh, qch, kch, vcT, vuT);

  for (int h0 = 0; h0 < H; h0 += G) {
    const int Gr = (H - h0 < G) ? (H - h0) : G;
    k_dsig<<<dim3(Gr, 136), 256, 0, stream>>>(quh, kuh, qch, vuh, vuT, sigb, DC, diagb, h0);
    k_scan<<<(Gr * KD + 255) / 256, 256, 0, stream>>>(DC, Gr * KD);
    k_favs<<<dim3(Gr, 128), 256, 0, stream>>>(qch, kch, DC, sigb, diagb, vcT, Oh, h0);
  }

  k_out<<<dim3(16, 8), 256, 0, stream>>>(Oh, woh, out);
}

// Round 3
// 338.867 us; speedup vs baseline: 1.1751x; 1.1069x over previous
//
#include <hip/hip_runtime.h>

using f16 = _Float16;
using half8  = __attribute__((ext_vector_type(8))) f16;
using half4v = __attribute__((ext_vector_type(4))) f16;
using float4v = __attribute__((ext_vector_type(4))) float;

#define DEV static __device__ __forceinline__

constexpr int N = 2048, DIM = 1024, H = 16, DH = 64, F6 = 6144;
constexpr int LDSH = 136;       // f16 epilogue row stride (halves)
constexpr int TS = 128 * 128;   // packed tile elements
constexpr int NTILES = 136;     // triangular 128x128 tiles per head
constexpr int KD = 2048 * 64;   // D/C elements per T-slice per head

DEV int PL(int i, int k) { return i * (i + 1) / 2 + k; }                  // lower, k<=i
DEV int PU(int a, int b) { return a * 16 - a * (a - 1) / 2 + (b - a); }   // upper, a<=b

template<int ROWS, int THREADS>
DEV void stage64(const f16* __restrict__ g, int strideHalves, f16* lds, int tid) {
#pragma unroll
  for (int q = 0; q < (ROWS * 8) / THREADS; ++q) {
    const int chunk = q * THREADS + tid;
    const int m = chunk >> 3, c = (chunk & 7) ^ (m & 7);
    const f16* gp = g + (size_t)m * strideHalves + c * 8;
    __builtin_amdgcn_global_load_lds(
        (const __attribute__((address_space(1))) unsigned int*)gp,
        (__attribute__((address_space(3))) unsigned int*)(lds + chunk * 8), 16, 0, 0);
  }
}

DEV half8 rdfrag(const f16* T, int m, int ks, int q) {
  const int c = (ks * 4 + q) ^ (m & 7);
  return *(const half8*)(T + m * 64 + c * 8);
}

// store one element into frag layout (inverse of rdfrag addressing)
DEV void wfrag(f16* T, int row, int col, f16 v) {
  T[row * 64 + ((((col >> 3) ^ (row & 7)) << 3) | (col & 7))] = v;
}

DEV void gemm64(const f16* As, const f16* Bs, int wm, int wn, int l, float4v acc[4][4]) {
  const int q = l >> 4, mm = l & 15;
#pragma unroll
  for (int ks = 0; ks < 2; ++ks) {
    half8 af[4], bf[4];
#pragma unroll
    for (int mi = 0; mi < 4; ++mi) af[mi] = rdfrag(As, wm + mm + mi * 16, ks, q);
#pragma unroll
    for (int ni = 0; ni < 4; ++ni) bf[ni] = rdfrag(Bs, wn + mm + ni * 16, ks, q);
#pragma unroll
    for (int mi = 0; mi < 4; ++mi)
#pragma unroll
      for (int ni = 0; ni < 4; ++ni)
        acc[mi][ni] = __builtin_amdgcn_mfma_f32_16x16x32_f16(af[mi], bf[ni], acc[mi][ni], 0, 0, 0);
  }
}

// p in [0,136) -> (ti,tk), tk<=ti.
DEV void decode_pair(int p, int& ti, int& tk) {
  int t = (int)((sqrtf(8.f * p + 1.f) - 1.f) * 0.5f);
  while (t * (t + 1) / 2 > p) --t;
  while ((t + 1) * (t + 2) / 2 <= p) ++t;
  const int i2 = p - t * (t + 1) / 2;
  ti = (15 - t) + i2;
  tk = i2;
}

__global__ __launch_bounds__(256) void k_cast(const float* __restrict__ s, f16* __restrict__ d, int n4) {
  int i = blockIdx.x * 256 + threadIdx.x;
  if (i < n4) {
    float4 v = ((const float4*)s)[i];
    half4v h;
    h[0] = (f16)v.x; h[1] = (f16)v.y; h[2] = (f16)v.z; h[3] = (f16)v.w;
    ((half4v*)d)[i] = h;
  }
}

// qkvs = x @ w_qkv^T; per-head scatter. vu additionally stored transposed (vuT[h][d][n]).
__global__ __launch_bounds__(256) void k_qkv(const f16* __restrict__ xh, const f16* __restrict__ wh,
                                             f16* __restrict__ quh, f16* __restrict__ kuh,
                                             f16* __restrict__ vuh, f16* __restrict__ qch,
                                             f16* __restrict__ kch, f16* __restrict__ vcT,
                                             f16* __restrict__ vuT) {
  __shared__ __align__(16) f16 lds[128 * LDSH];
  f16* As = lds; f16* Bs = lds + 128 * 64;
  const int tid = threadIdx.x, w = tid >> 6, l = tid & 63;
  const int tm = blockIdx.x * 128, tf = blockIdx.y * 128;
  const int wm = (w >> 1) * 64, wn = (w & 1) * 64;
  float4v acc[4][4] = {};
  for (int k0 = 0; k0 < DIM; k0 += 64) {
    stage64<128, 256>(xh + (size_t)tm * DIM + k0, DIM, As, tid);
    stage64<128, 256>(wh + (size_t)tf * DIM + k0, DIM, Bs, tid);
    __syncthreads();
    gemm64(As, Bs, wm, wn, l, acc);
    __syncthreads();
  }
  const int rbase = (l >> 4) * 4, cidx = l & 15;
  const int t = tf >> 10;
  const float sc = (t == 0 || t == 3) ? 0.125f : 1.f;
  if (t == 5 || t == 2) {
    f16* T = (t == 5) ? vcT : vuT;
#pragma unroll
    for (int mi = 0; mi < 4; ++mi)
#pragma unroll
      for (int ni = 0; ni < 4; ++ni) {
        const int f = tf + wn + ni * 16 + cidx;
        const int h = (f & 1023) >> 6, d = f & 63;
        half4v p;
#pragma unroll
        for (int r = 0; r < 4; ++r) p[r] = (f16)acc[mi][ni][r];
        *(half4v*)(T + ((size_t)h * DH + d) * N + (tm + wm + mi * 16 + rbase)) = p;
      }
  }
  if (t != 5) {
#pragma unroll
    for (int mi = 0; mi < 4; ++mi)
#pragma unroll
      for (int ni = 0; ni < 4; ++ni)
#pragma unroll
        for (int r = 0; r < 4; ++r)
          lds[(wm + mi * 16 + rbase + r) * LDSH + wn + ni * 16 + cidx] = (f16)(acc[mi][ni][r] * sc);
    __syncthreads();
    f16* dst = (t == 0) ? quh : (t == 1) ? kuh : (t == 2) ? vuh : (t == 3) ? qch : kch;
    const int hb = (tf & 1023) >> 6;
#pragma unroll
    for (int q = 0; q < 8; ++q) {
      const int idx = q * 256 + tid, row = idx >> 4, c = idx & 15;
      const int h = hb + (c >> 3), d0 = (c & 7) * 8, n = tm + row;
      *(half8*)(dst + ((size_t)h * N + n) * DH + d0) = *(const half8*)(lds + row * LDSH + c * 8);
    }
  }
}

// Per pair (a<=b): sig tile PU(a,b) = triu1(sigmoid(qu[a].ku[b]^T)), computed ONCE;
// fused D-contribution D^{(b)}[a-rows] = sigtile @ vu[b-block]; for a==b also the
// diagonal term1 tile tril(qc[a].vu[a]^T). Grid (Gr,136): blockIdx.x = head (XCD pin).
__global__ __launch_bounds__(256) void k_dsig(const f16* __restrict__ quh, const f16* __restrict__ kuh,
                                              const f16* __restrict__ qch, const f16* __restrict__ vuh,
                                              const f16* __restrict__ vuT,
                                              f16* __restrict__ sigb, f16* __restrict__ DC,
                                              f16* __restrict__ diagb, int h0) {
  __shared__ __align__(16) f16 L[32768];  // quA 8192 | kuB 8192 (reused vtB0/vtB1) | s1 8192 | s2 8192
  f16* quA = L; f16* kuB = L + 8192; f16* s1 = L + 16384; f16* s2 = L + 24576;
  int b, a;
  decode_pair(blockIdx.y, b, a);
  const int hl = blockIdx.x, h = h0 + hl;
  const int tid = threadIdx.x, w = tid >> 6, l = tid & 63;
  const int q = l >> 4, m = l & 15;
  const int wm = (w >> 1) * 64, wn = (w & 1) * 64;
  const size_t ho = (size_t)h * N * DH;

  stage64<128, 256>(quh + ho + (size_t)(a * 128) * DH, DH, quA, tid);
  stage64<128, 256>(kuh + ho + (size_t)(b * 128) * DH, DH, kuB, tid);
  __syncthreads();
  float4v acc[4][4] = {};
  gemm64(quA, kuB, wm, wn, l, acc);  // qu[a] . ku[b]^T
  __syncthreads();  // quA/kuB reads done
  stage64<64, 256>(vuT + (size_t)h * DH * N + b * 128, N, kuB, tid);
  stage64<64, 256>(vuT + (size_t)h * DH * N + b * 128 + 64, N, kuB + 4096, tid);
  // sigmoid + strict-upper mask -> swizzled A-frag panels s1/s2
#pragma unroll
  for (int mi = 0; mi < 4; ++mi)
#pragma unroll
    for (int ni = 0; ni < 4; ++ni)
#pragma unroll
      for (int r = 0; r < 4; ++r) {
        const int row = wm + mi * 16 + q * 4 + r;   // k-local
        const int col = wn + ni * 16 + m;           // j-local
        const float x = acc[mi][ni][r];
        const f16 sv = (b * 128 + col > a * 128 + row) ? (f16)(1.f / (1.f + __expf(-x))) : (f16)0.f;
        wfrag((col < 64) ? s1 : s2, row, col & 63, sv);
      }
  __syncthreads();  // panels visible; vtB staged
  {
    f16* Sg = sigb + ((size_t)hl * NTILES + PU(a, b)) * TS;
#pragma unroll
    for (int qq = 0; qq < 8; ++qq) {
      const int idx = qq * 256 + tid, row = idx >> 4, c = idx & 15;
      const f16* p = ((c >> 3) ? s2 : s1) + row * 64 + (((c & 7) ^ (row & 7)) << 3);
      *(half8*)(Sg + (size_t)row * 128 + c * 8) = *(const half8*)p;
    }
  }
  float4v dacc[2][4] = {};
#pragma unroll
  for (int p = 0; p < 2; ++p)
#pragma unroll
    for (int ks = 0; ks < 2; ++ks) {
      half8 bf[4], af[2];
#pragma unroll
      for (int ni = 0; ni < 4; ++ni) bf[ni] = rdfrag(kuB + p * 4096, ni * 16 + m, ks, q);
#pragma unroll
      for (int mi = 0; mi < 2; ++mi) af[mi] = rdfrag(p ? s2 : s1, w * 32 + mi * 16 + m, ks, q);
#pragma unroll
      for (int mi = 0; mi < 2; ++mi)
#pragma unroll
        for (int ni = 0; ni < 4; ++ni)
          dacc[mi][ni] = __builtin_amdgcn_mfma_f32_16x16x32_f16(af[mi], bf[ni], dacc[mi][ni], 0, 0, 0);
    }
  __syncthreads();
  if (a == b) {
    stage64<128, 256>(qch + ho + (size_t)(a * 128) * DH, DH, quA, tid);
    stage64<128, 256>(vuh + ho + (size_t)(a * 128) * DH, DH, kuB, tid);
  }
  {
    f16* epsD = s1;
#pragma unroll
    for (int mi = 0; mi < 2; ++mi)
#pragma unroll
      for (int ni = 0; ni < 4; ++ni)
#pragma unroll
        for (int r = 0; r < 4; ++r)
          epsD[(w * 32 + mi * 16 + q * 4 + r) * 68 + ni * 16 + m] = (f16)dacc[mi][ni][r];
    __syncthreads();
    f16* Dg = DC + ((size_t)hl * 16 + b) * KD + (size_t)(a * 128) * 64;
#pragma unroll
    for (int qq = 0; qq < 4; ++qq) {
      const int idx = qq * 256 + tid, row = idx >> 3, c = idx & 7;
      *(half8*)(Dg + (size_t)row * 64 + c * 8) = *(const half8*)(epsD + row * 68 + c * 8);
    }
  }
  if (a == b) {
    float4v tacc[4][4] = {};
    gemm64(quA, kuB, wm, wn, l, tacc);  // qc[a] . vu[a]^T
    f16* Tg = diagb + ((size_t)hl * 16 + a) * TS;
#pragma unroll
    for (int mi = 0; mi < 4; ++mi)
#pragma unroll
      for (int ni = 0; ni < 4; ++ni)
#pragma unroll
        for (int r = 0; r < 4; ++r) {
          const int row = wm + mi * 16 + q * 4 + r, col = wn + ni * 16 + m;
          Tg[(size_t)row * 128 + col] = (col <= row) ? (f16)tacc[mi][ni][r] : (f16)0.f;
        }
  }
}

// In-place exclusive prefix over T: C^{(T)} = sum_{T'<T} D^{(T')}, f32 accumulate.
__global__ __launch_bounds__(256) void k_scan(f16* __restrict__ DC, int total) {
  const int idx = blockIdx.x * 256 + threadIdx.x;
  if (idx >= total) return;
  const int g = idx >> 17, off = idx & (KD - 1);
  const int a = off >> 13;
  f16* p = DC + (size_t)g * 16 * KD + off;
  float s = 0.f;
#pragma unroll
  for (int T = 0; T < 16; ++T) {
    const float v = (T >= a) ? (float)p[(size_t)T * KD] : 0.f;
    p[(size_t)T * KD] = (f16)s;
    s += v;
  }
}

// Fused scores + online-softmax + PV. Block = (head hl = blockIdx.x [XCD pin],
// 32-row tile mt). 4 waves split 64-col jt-chunks (disjoint work -> register-direct
// B-frag loads; no LDS staging, no barriers in the main loop).
// vs round-0: (1) CU-balanced pairing — CU c hosts y=c/8 and y=c/8+32; mapping
// y<32 -> mt=63-2y, y>=32 -> mt=2(y-32) makes each CU's two blocks total ~65
// chunks (was 16-vs-1 long-pole imbalance -> 11% time-avg occupancy).
// (2) explicit load hoisting: all C/kc/Sg B-frags for the score phases issue
// BEFORE the MFMA chains, V-frags before the softmax VALU chain — uses the free
// 129-256 VGPR tier (2 waves/SIMD either way) to collapse ~8 serialized
// load-stall windows per chunk into ~2.
__global__ __launch_bounds__(256) void k_favs(const f16* __restrict__ qch, const f16* __restrict__ kch,
                                              const f16* __restrict__ DC, const f16* __restrict__ sigb,
                                              const f16* __restrict__ diagb, const f16* __restrict__ vcT,
                                              f16* __restrict__ Oh, int h0) {
  __shared__ float mlds[4][32], llds[4][32];
  __shared__ __align__(16) float olds[32][68];
  __shared__ __align__(16) f16 plds[4][32 * 64];
  const int hl = blockIdx.x, h = h0 + hl;
  const int y = (int)blockIdx.y;
  const int mt = (y < 32) ? (63 - 2 * y) : (2 * (y - 32));  // CU-pair balance
  const int tid = threadIdx.x, w = tid >> 6, l = tid & 63;
  const int q = l >> 4, m = l & 15;
  const int ti = mt >> 2, r0 = mt * 32;
  const size_t ho = (size_t)h * N * DH;
  const f16* qc = qch + ho;
  const f16* kc = kch + ho;
  const f16* Cb = DC + ((size_t)hl * 16 + ti) * KD;
  const f16* Td = diagb + ((size_t)hl * 16 + ti) * TS;
  const f16* Sgb = sigb + (size_t)hl * NTILES * TS;
  const f16* V = vcT + (size_t)h * DH * N;
  f16* pw = plds[w];

  // cached A-frags: qc rows [r0,r0+32) and T1diag rows (local) [dr,dr+32) x 128 j
  half8 qcA[2][2], tdA[2][4];
  const int dr = (mt & 3) * 32;
#pragma unroll
  for (int mi = 0; mi < 2; ++mi) {
#pragma unroll
    for (int ks = 0; ks < 2; ++ks)
      qcA[mi][ks] = *(const half8*)(qc + (size_t)(r0 + mi * 16 + m) * DH + ks * 32 + q * 8);
#pragma unroll
    for (int ks = 0; ks < 4; ++ks)
      tdA[mi][ks] = *(const half8*)(Td + (size_t)(dr + mi * 16 + m) * 128 + ks * 32 + q * 8);
  }

  float4v o[2][4] = {};
  float mrun[2][4], lrun[2][4];
#pragma unroll
  for (int mi = 0; mi < 2; ++mi)
#pragma unroll
    for (int r = 0; r < 4; ++r) { mrun[mi][r] = -1e30f; lrun[mi][r] = 0.f; }

  const int jtmax = mt >> 1;
  for (int jt = w; jt <= jtmax; jt += 4) {
    const int k0 = jt * 64;
    const int tkt = jt >> 1, koff = (jt & 1) * 64;
    const f16* Sg = Sgb + (size_t)PU(tkt, ti) * TS;
    // ---- issue phase-1 (C), phase-3 (kc), and first-half phase-2 (Sg) loads ----
    half8 bC[2][4], bK[2][4], bS0[2][4];
#pragma unroll
    for (int ks = 0; ks < 2; ++ks)
#pragma unroll
      for (int ni = 0; ni < 4; ++ni)
        bC[ks][ni] = *(const half8*)(Cb + (size_t)(k0 + ni * 16 + m) * 64 + ks * 32 + q * 8);
#pragma unroll
    for (int ks = 0; ks < 2; ++ks)
#pragma unroll
      for (int ni = 0; ni < 4; ++ni)
        bK[ks][ni] = *(const half8*)(kc + (size_t)(k0 + ni * 16 + m) * DH + ks * 32 + q * 8);
#pragma unroll
    for (int ks = 0; ks < 2; ++ks)
#pragma unroll
      for (int ni = 0; ni < 4; ++ni)
        bS0[ks][ni] = *(const half8*)(Sg + (size_t)(koff + ni * 16 + m) * 128 + ks * 32 + q * 8);
    float4v s[2][4] = {};
    // phase 1: qc . C^{(ti)}[k]^T  (K=64)
#pragma unroll
    for (int ks = 0; ks < 2; ++ks)
#pragma unroll
      for (int mi = 0; mi < 2; ++mi)
#pragma unroll
        for (int ni = 0; ni < 4; ++ni)
          s[mi][ni] = __builtin_amdgcn_mfma_f32_16x16x32_f16(qcA[mi][ks], bC[ks][ni], s[mi][ni], 0, 0, 0);
    // issue second-half phase-2 (Sg ks=2,3) loads
    half8 bS1[2][4];
#pragma unroll
    for (int ks = 0; ks < 2; ++ks)
#pragma unroll
      for (int ni = 0; ni < 4; ++ni)
        bS1[ks][ni] = *(const half8*)(Sg + (size_t)(koff + ni * 16 + m) * 128 + (ks + 2) * 32 + q * 8);
    // phase 2a: + T1diag . sig^T  (ks 0,1)
#pragma unroll
    for (int ks = 0; ks < 2; ++ks)
#pragma unroll
      for (int mi = 0; mi < 2; ++mi)
#pragma unroll
        for (int ni = 0; ni < 4; ++ni)
          s[mi][ni] = __builtin_amdgcn_mfma_f32_16x16x32_f16(tdA[mi][ks], bS0[ks][ni], s[mi][ni], 0, 0, 0);
    // issue V loads (consumed after softmax -> long latency window)
    half8 bV[2][4];
#pragma unroll
    for (int ks = 0; ks < 2; ++ks)
#pragma unroll
      for (int ni = 0; ni < 4; ++ni)
        bV[ks][ni] = *(const half8*)(V + (size_t)(ni * 16 + m) * N + k0 + ks * 32 + q * 8);
    // phase 2b: (ks 2,3)
#pragma unroll
    for (int ks = 0; ks < 2; ++ks)
#pragma unroll
      for (int mi = 0; mi < 2; ++mi)
#pragma unroll
        for (int ni = 0; ni < 4; ++ni)
          s[mi][ni] = __builtin_amdgcn_mfma_f32_16x16x32_f16(tdA[mi][ks + 2], bS1[ks][ni], s[mi][ni], 0, 0, 0);
    // s := -silu(Su)
#pragma unroll
    for (int mi = 0; mi < 2; ++mi)
#pragma unroll
      for (int ni = 0; ni < 4; ++ni)
#pragma unroll
        for (int r = 0; r < 4; ++r) {
          const float x = s[mi][ni][r];
          s[mi][ni][r] = -(x / (1.f + __expf(-x)));
        }
    // phase 3: + Sc = qc . kc^T  (K=64, bK preloaded at chunk top)
#pragma unroll
    for (int ks = 0; ks < 2; ++ks)
#pragma unroll
      for (int mi = 0; mi < 2; ++mi)
#pragma unroll
        for (int ni = 0; ni < 4; ++ni)
          s[mi][ni] = __builtin_amdgcn_mfma_f32_16x16x32_f16(qcA[mi][ks], bK[ks][ni], s[mi][ni], 0, 0, 0);
    // causal mask (only the diagonal chunk has cols > some rows)
    if (jt == jtmax) {
#pragma unroll
      for (int mi = 0; mi < 2; ++mi)
#pragma unroll
        for (int ni = 0; ni < 4; ++ni) {
          const int col = k0 + ni * 16 + m;
#pragma unroll
          for (int r = 0; r < 4; ++r)
            if (col > r0 + mi * 16 + q * 4 + r) s[mi][ni][r] = -1e30f;
        }
    }
    // online softmax (C-layout: rows = mi*16 + q*4 + r)
    float al[2][4], ts[2][4];
#pragma unroll
    for (int mi = 0; mi < 2; ++mi)
#pragma unroll
      for (int r = 0; r < 4; ++r) {
        float tmx = fmaxf(fmaxf(s[mi][0][r], s[mi][1][r]), fmaxf(s[mi][2][r], s[mi][3][r]));
#pragma unroll
        for (int x = 1; x < 16; x <<= 1) tmx = fmaxf(tmx, __shfl_xor(tmx, x));
        const float nm = fmaxf(mrun[mi][r], tmx);
        al[mi][r] = __expf(mrun[mi][r] - nm);
        mrun[mi][r] = nm;
        ts[mi][r] = 0.f;
      }
#pragma unroll
    for (int mi = 0; mi < 2; ++mi)
#pragma unroll
      for (int ni = 0; ni < 4; ++ni)
#pragma unroll
        for (int r = 0; r < 4; ++r) {
          const float p = __expf(s[mi][ni][r] - mrun[mi][r]);
          wfrag(pw, mi * 16 + q * 4 + r, ni * 16 + m, (f16)p);
          ts[mi][r] += p;
        }
#pragma unroll
    for (int mi = 0; mi < 2; ++mi)
#pragma unroll
      for (int r = 0; r < 4; ++r) {
#pragma unroll
        for (int x = 1; x < 16; x <<= 1) ts[mi][r] += __shfl_xor(ts[mi][r], x);
        lrun[mi][r] = lrun[mi][r] * al[mi][r] + ts[mi][r];
#pragma unroll
        for (int ni = 0; ni < 4; ++ni) o[mi][ni][r] *= al[mi][r];
      }
    // PV: O += P(A-layout via LDS) . vc(bV preloaded before softmax)
#pragma unroll
    for (int ks = 0; ks < 2; ++ks) {
      half8 af[2];
#pragma unroll
      for (int mi = 0; mi < 2; ++mi) af[mi] = rdfrag(pw, mi * 16 + m, ks, q);
#pragma unroll
      for (int mi = 0; mi < 2; ++mi)
#pragma unroll
        for (int ni = 0; ni < 4; ++ni)
          o[mi][ni] = __builtin_amdgcn_mfma_f32_16x16x32_f16(af[mi], bV[ks][ni], o[mi][ni], 0, 0, 0);
    }
  }
  // merge the 4 waves
  if (m == 0)
#pragma unroll
    for (int mi = 0; mi < 2; ++mi)
#pragma unroll
      for (int r = 0; r < 4; ++r) {
        mlds[w][mi * 16 + q * 4 + r] = mrun[mi][r];
        llds[w][mi * 16 + q * 4 + r] = lrun[mi][r];
      }
  __syncthreads();
#pragma unroll
  for (int mi = 0; mi < 2; ++mi)
#pragma unroll
    for (int r = 0; r < 4; ++r) {
      const int row = mi * 16 + q * 4 + r;
      const float mstar = fmaxf(fmaxf(mlds[0][row], mlds[1][row]), fmaxf(mlds[2][row], mlds[3][row]));
      const float sw = __expf(mlds[w][row] - mstar);
#pragma unroll
      for (int ni = 0; ni < 4; ++ni) o[mi][ni][r] *= sw;
    }
#pragma unroll
  for (int t = 0; t < 4; ++t) {
    if (w == t) {
#pragma unroll
      for (int mi = 0; mi < 2; ++mi)
#pragma unroll
        for (int ni = 0; ni < 4; ++ni)
#pragma unroll
          for (int r = 0; r < 4; ++r) {
            const int row = mi * 16 + q * 4 + r, col = ni * 16 + m;
            if (t == 0) olds[row][col] = o[mi][ni][r];
            else olds[row][col] += o[mi][ni][r];
          }
    }
    __syncthreads();
  }
  const int row = tid >> 3, c = tid & 7;
  const float mstar = fmaxf(fmaxf(mlds[0][row], mlds[1][row]), fmaxf(mlds[2][row], mlds[3][row]));
  float denom = 0.f;
#pragma unroll
  for (int t = 0; t < 4; ++t) denom += __expf(mlds[t][row] - mstar) * llds[t][row];
  const float inv = 1.f / denom;
  half8 o8;
#pragma unroll
  for (int e = 0; e < 8; ++e) o8[e] = (f16)(olds[row][c * 8 + e] * inv);
  *(half8*)(Oh + (size_t)(mt * 32 + row) * (H * DH) + h * DH + c * 8) = o8;
}

// out = O @ w_out^T, fp32 result.
__global__ __launch_bounds__(256) void k_out(const f16* __restrict__ Oh, const f16* __restrict__ wo,
                                             float* __restrict__ out) {
  __shared__ __align__(16) f16 lds[128 * LDSH];
  f16* As = lds; f16* Bs = lds + 128 * 64;
  const int tid = threadIdx.x, w = tid >> 6, l = tid & 63;
  const int tm = blockIdx.x * 128, tn = blockIdx.y * 128;
  const int wm = (w >> 1) * 64, wn = (w & 1) * 64;
  float4v acc[4][4] = {};
  for (int k0 = 0; k0 < DIM; k0 += 64) {
    stage64<128, 256>(Oh + (size_t)tm * DIM + k0, DIM, As, tid);
    stage64<128, 256>(wo + (size_t)tn * DIM + k0, DIM, Bs, tid);
    __syncthreads();
    gemm64(As, Bs, wm, wn, l, acc);
    __syncthreads();
  }
  const int rbase = (l >> 4) * 4, cidx = l & 15;
#pragma unroll
  for (int mi = 0; mi < 4; ++mi)
#pragma unroll
    for (int ni = 0; ni < 4; ++ni)
#pragma unroll
      for (int r = 0; r < 4; ++r) {
        const int n = tm + wm + mi * 16 + rbase + r;
        const int dmo = tn + wn + ni * 16 + cidx;
        out[(size_t)n * DIM + dmo] = acc[mi][ni][r];
      }
}

extern "C" void kernel_launch(void* const* d_in, const int* in_sizes, int n_in,
                              void* d_out, int out_size, void* d_ws, size_t ws_size,
                              hipStream_t stream) {
  const float* x = (const float*)d_in[0];
  const float* wqkv = (const float*)d_in[1];
  const float* wout = (const float*)d_in[2];
  float* out = (float*)d_out;
  char* ws = (char*)d_ws;

  size_t off = 0;
  auto alloc = [&](size_t b) { size_t o = off; off += (b + 255) & ~(size_t)255; return o; };
  f16* xh  = (f16*)(ws + alloc((size_t)N * DIM * 2));
  f16* wqh = (f16*)(ws + alloc((size_t)F6 * DIM * 2));
  f16* woh = (f16*)(ws + alloc((size_t)DIM * H * DH * 2));
  f16* quh = (f16*)(ws + alloc((size_t)H * N * DH * 2));
  f16* kuh = (f16*)(ws + alloc((size_t)H * N * DH * 2));
  f16* vuh = (f16*)(ws + alloc((size_t)H * N * DH * 2));
  f16* qch = (f16*)(ws + alloc((size_t)H * N * DH * 2));
  f16* kch = (f16*)(ws + alloc((size_t)H * N * DH * 2));
  f16* vcT = (f16*)(ws + alloc((size_t)H * DH * N * 2));
  f16* vuT = (f16*)(ws + alloc((size_t)H * DH * N * 2));
  f16* Oh  = (f16*)(ws + alloc((size_t)N * H * DH * 2));
  const size_t persist = off;

  // per head: sig tiles + D/C + diag tiles (scob eliminated by k_favs fusion)
  const size_t per_head = ((size_t)NTILES * TS + (size_t)16 * KD + (size_t)16 * TS) * 2;
  int G = (ws_size > persist + 4096) ? (int)((ws_size - persist - 4096) / per_head) : 1;
  if (G < 1) G = 1;
  if (G > 16) G = 16;
  {  // normalize so rounds are evenly sized (prefer G=8 for head->XCD pinning)
    const int R = (H + G - 1) / G;
    G = (H + R - 1) / R;
  }
  f16* sigb  = (f16*)(ws + alloc((size_t)G * NTILES * TS * 2));
  f16* DC    = (f16*)(ws + alloc((size_t)G * 16 * KD * 2));
  f16* diagb = (f16*)(ws + alloc((size_t)G * 16 * TS * 2));

  k_cast<<<(N * DIM / 4 + 255) / 256, 256, 0, stream>>>(x, xh, N * DIM / 4);
  k_cast<<<(F6 * DIM / 4 + 255) / 256, 256, 0, stream>>>(wqkv, wqh, F6 * DIM / 4);
  k_cast<<<(DIM * H * DH / 4 + 255) / 256, 256, 0, stream>>>(wout, woh, DIM * H * DH / 4);

  k_qkv<<<dim3(N / 128, F6 / 128), 256, 0, stream>>>(xh, wqh, quh, kuh, vuh, qch, kch, vcT, vuT);

  for (int h0 = 0; h0 < H; h0 += G) {
    const int Gr = (H - h0 < G) ? (H - h0) : G;
    k_dsig<<<dim3(Gr, 136), 256, 0, stream>>>(quh, kuh, qch, vuh, vuT, sigb, DC, diagb, h0);
    k_scan<<<(Gr * KD + 255) / 256, 256, 0, stream>>>(DC, Gr * KD);
    k_favs<<<dim3(Gr, 64), 256, 0, stream>>>(qch, kch, DC, sigb, diagb, vcT, Oh, h0);
  }

  k_out<<<dim3(16, 8), 256, 0, stream>>>(Oh, woh, out);
}

// Round 4
// 296.839 us; speedup vs baseline: 1.3415x; 1.1416x over previous
//
#include <hip/hip_runtime.h>

using f16 = _Float16;
using half8  = __attribute__((ext_vector_type(8))) f16;
using half4v = __attribute__((ext_vector_type(4))) f16;
using float4v = __attribute__((ext_vector_type(4))) float;

#define DEV static __device__ __forceinline__

constexpr int N = 2048, DIM = 1024, H = 16, DH = 64, F6 = 6144;
constexpr int LDSH = 136;       // f16 epilogue row stride (halves)
constexpr int TS = 128 * 128;   // packed tile elements
constexpr int NTILES = 136;     // triangular 128x128 tiles per head
constexpr int KD = 2048 * 64;   // D/C elements per T-slice per head

// FRAG-MAJOR PANEL LAYOUT (new): 64-row x 64-col panel stored so that the half8
// a lane (q,m) consumes for (ks,ni) sits at element offset
//   (ks*256 + q*64 + ni*16 + m) * 8
// -> a wave's B-frag load touches 8 cache lines (coalesced) instead of 64
//    (the old row-major 128-B-stride gather). Applied to DC, sigb, kch, vcT.

DEV int PL(int i, int k) { return i * (i + 1) / 2 + k; }                  // lower, k<=i
DEV int PU(int a, int b) { return a * 16 - a * (a - 1) / 2 + (b - a); }   // upper, a<=b

template<int ROWS, int THREADS>
DEV void stage64(const f16* __restrict__ g, int strideHalves, f16* lds, int tid) {
#pragma unroll
  for (int q = 0; q < (ROWS * 8) / THREADS; ++q) {
    const int chunk = q * THREADS + tid;
    const int m = chunk >> 3, c = (chunk & 7) ^ (m & 7);
    const f16* gp = g + (size_t)m * strideHalves + c * 8;
    __builtin_amdgcn_global_load_lds(
        (const __attribute__((address_space(1))) unsigned int*)gp,
        (__attribute__((address_space(3))) unsigned int*)(lds + chunk * 8), 16, 0, 0);
  }
}

DEV half8 rdfrag(const f16* T, int m, int ks, int q) {
  const int c = (ks * 4 + q) ^ (m & 7);
  return *(const half8*)(T + m * 64 + c * 8);
}

// store one element into frag layout (inverse of rdfrag addressing)
DEV void wfrag(f16* T, int row, int col, f16 v) {
  T[row * 64 + ((((col >> 3) ^ (row & 7)) << 3) | (col & 7))] = v;
}

DEV void gemm64(const f16* As, const f16* Bs, int wm, int wn, int l, float4v acc[4][4]) {
  const int q = l >> 4, mm = l & 15;
#pragma unroll
  for (int ks = 0; ks < 2; ++ks) {
    half8 af[4], bf[4];
#pragma unroll
    for (int mi = 0; mi < 4; ++mi) af[mi] = rdfrag(As, wm + mm + mi * 16, ks, q);
#pragma unroll
    for (int ni = 0; ni < 4; ++ni) bf[ni] = rdfrag(Bs, wn + mm + ni * 16, ks, q);
#pragma unroll
    for (int mi = 0; mi < 4; ++mi)
#pragma unroll
      for (int ni = 0; ni < 4; ++ni)
        acc[mi][ni] = __builtin_amdgcn_mfma_f32_16x16x32_f16(af[mi], bf[ni], acc[mi][ni], 0, 0, 0);
  }
}

// p in [0,136) -> (ti,tk), tk<=ti.
DEV void decode_pair(int p, int& ti, int& tk) {
  int t = (int)((sqrtf(8.f * p + 1.f) - 1.f) * 0.5f);
  while (t * (t + 1) / 2 > p) --t;
  while ((t + 1) * (t + 2) / 2 <= p) ++t;
  const int i2 = p - t * (t + 1) / 2;
  ti = (15 - t) + i2;
  tk = i2;
}

__global__ __launch_bounds__(256) void k_cast(const float* __restrict__ s, f16* __restrict__ d, int n4) {
  int i = blockIdx.x * 256 + threadIdx.x;
  if (i < n4) {
    float4 v = ((const float4*)s)[i];
    half4v h;
    h[0] = (f16)v.x; h[1] = (f16)v.y; h[2] = (f16)v.z; h[3] = (f16)v.w;
    ((half4v*)d)[i] = h;
  }
}

// qkvs = x @ w_qkv^T; per-head scatter. vu additionally stored transposed (vuT[h][d][n]).
// kch and vcT are written in FRAG-MAJOR panel layout (consumed only by k_favs B-frags).
__global__ __launch_bounds__(256) void k_qkv(const f16* __restrict__ xh, const f16* __restrict__ wh,
                                             f16* __restrict__ quh, f16* __restrict__ kuh,
                                             f16* __restrict__ vuh, f16* __restrict__ qch,
                                             f16* __restrict__ kch, f16* __restrict__ vcT,
                                             f16* __restrict__ vuT) {
  __shared__ __align__(16) f16 lds[128 * LDSH];
  f16* As = lds; f16* Bs = lds + 128 * 64;
  const int tid = threadIdx.x, w = tid >> 6, l = tid & 63;
  const int tm = blockIdx.x * 128, tf = blockIdx.y * 128;
  const int wm = (w >> 1) * 64, wn = (w & 1) * 64;
  float4v acc[4][4] = {};
  for (int k0 = 0; k0 < DIM; k0 += 64) {
    stage64<128, 256>(xh + (size_t)tm * DIM + k0, DIM, As, tid);
    stage64<128, 256>(wh + (size_t)tf * DIM + k0, DIM, Bs, tid);
    __syncthreads();
    gemm64(As, Bs, wm, wn, l, acc);
    __syncthreads();
  }
  const int rbase = (l >> 4) * 4, cidx = l & 15;
  const int t = tf >> 10;
  const float sc = (t == 0 || t == 3) ? 0.125f : 1.f;
  if (t == 5 || t == 2) {
#pragma unroll
    for (int mi = 0; mi < 4; ++mi)
#pragma unroll
      for (int ni = 0; ni < 4; ++ni) {
        const int f = tf + wn + ni * 16 + cidx;
        const int h = (f & 1023) >> 6, d = f & 63;
        const int n = tm + wm + mi * 16 + rbase;
        half4v p;
#pragma unroll
        for (int r = 0; r < 4; ++r) p[r] = (f16)acc[mi][ni][r];
        if (t == 5) {
          // vcT frag panel: rows=d, cols=n; panel = n/64
          const int ks2 = (n & 63) >> 5, q2 = (n >> 3) & 3;
          const int inner = ks2 * 256 + q2 * 64 + (d >> 4) * 16 + (d & 15);
          *(half4v*)(vcT + (size_t)h * DH * N + (size_t)(n >> 6) * 4096 +
                     (size_t)inner * 8 + (n & 7)) = p;
        } else {
          *(half4v*)(vuT + ((size_t)h * DH + d) * N + n) = p;
        }
      }
  }
  if (t != 5) {
#pragma unroll
    for (int mi = 0; mi < 4; ++mi)
#pragma unroll
      for (int ni = 0; ni < 4; ++ni)
#pragma unroll
        for (int r = 0; r < 4; ++r)
          lds[(wm + mi * 16 + rbase + r) * LDSH + wn + ni * 16 + cidx] = (f16)(acc[mi][ni][r] * sc);
    __syncthreads();
    const int hb = (tf & 1023) >> 6;
    if (t == 4) {
      // kch frag panels: rows=k(seq), cols=d; contiguous dst, ~conflict-free lds src
#pragma unroll
      for (int qq = 0; qq < 8; ++qq) {
        const int idx = qq * 256 + tid;          // 2048 half8 = 2 heads x 1024
        const int hh = idx >> 10, f = idx & 1023;
        const int pl = f >> 9, inner = f & 511;
        const int m2 = inner & 15, ni2 = (inner >> 4) & 3, q2 = (inner >> 6) & 3, ks2 = inner >> 8;
        const int row = pl * 64 + ni2 * 16 + m2;
        const int col = hh * 64 + ks2 * 32 + q2 * 8;
        *(half8*)(kch + (size_t)(hb + hh) * N * DH + ((size_t)(tm >> 6) + pl) * 4096 +
                  (size_t)inner * 8) = *(const half8*)(lds + row * LDSH + col);
      }
    } else {
      f16* dst = (t == 0) ? quh : (t == 1) ? kuh : (t == 2) ? vuh : qch;
#pragma unroll
      for (int q = 0; q < 8; ++q) {
        const int idx = q * 256 + tid, row = idx >> 4, c = idx & 15;
        const int h = hb + (c >> 3), d0 = (c & 7) * 8, n = tm + row;
        *(half8*)(dst + ((size_t)h * N + n) * DH + d0) = *(const half8*)(lds + row * LDSH + c * 8);
      }
    }
  }
}

// Per pair (a<=b): sig tile PU(a,b) = triu1(sigmoid(qu[a].ku[b]^T)), computed ONCE;
// fused D-contribution D^{(b)}[a-rows] = sigtile @ vu[b-block]; for a==b also the
// diagonal term1 tile tril(qc[a].vu[a]^T). Grid (Gr,136): blockIdx.x = head (XCD pin).
// sigb and DC are written in FRAG-MAJOR layout (contiguous dst half8 stores).
__global__ __launch_bounds__(256) void k_dsig(const f16* __restrict__ quh, const f16* __restrict__ kuh,
                                              const f16* __restrict__ qch, const f16* __restrict__ vuh,
                                              const f16* __restrict__ vuT,
                                              f16* __restrict__ sigb, f16* __restrict__ DC,
                                              f16* __restrict__ diagb, int h0) {
  __shared__ __align__(16) f16 L[32768];  // quA 8192 | kuB 8192 (reused vtB0/vtB1) | s1 8192 | s2 8192
  f16* quA = L; f16* kuB = L + 8192; f16* s1 = L + 16384; f16* s2 = L + 24576;
  int b, a;
  decode_pair(blockIdx.y, b, a);
  const int hl = blockIdx.x, h = h0 + hl;
  const int tid = threadIdx.x, w = tid >> 6, l = tid & 63;
  const int q = l >> 4, m = l & 15;
  const int wm = (w >> 1) * 64, wn = (w & 1) * 64;
  const size_t ho = (size_t)h * N * DH;

  stage64<128, 256>(quh + ho + (size_t)(a * 128) * DH, DH, quA, tid);
  stage64<128, 256>(kuh + ho + (size_t)(b * 128) * DH, DH, kuB, tid);
  __syncthreads();
  float4v acc[4][4] = {};
  gemm64(quA, kuB, wm, wn, l, acc);  // qu[a] . ku[b]^T
  __syncthreads();  // quA/kuB reads done
  stage64<64, 256>(vuT + (size_t)h * DH * N + b * 128, N, kuB, tid);
  stage64<64, 256>(vuT + (size_t)h * DH * N + b * 128 + 64, N, kuB + 4096, tid);
  // sigmoid + strict-upper mask -> swizzled A-frag panels s1/s2
#pragma unroll
  for (int mi = 0; mi < 4; ++mi)
#pragma unroll
    for (int ni = 0; ni < 4; ++ni)
#pragma unroll
      for (int r = 0; r < 4; ++r) {
        const int row = wm + mi * 16 + q * 4 + r;   // k-local
        const int col = wn + ni * 16 + m;           // j-local
        const float x = acc[mi][ni][r];
        const f16 sv = (b * 128 + col > a * 128 + row) ? (f16)(1.f / (1.f + __expf(-x))) : (f16)0.f;
        wfrag((col < 64) ? s1 : s2, row, col & 63, sv);
      }
  __syncthreads();  // panels visible; vtB staged
  {
    // frag-major store: dst = Sg + idx*8 (contiguous); src from swizzled s1/s2
    f16* Sg = sigb + ((size_t)hl * NTILES + PU(a, b)) * TS;
#pragma unroll
    for (int qq = 0; qq < 8; ++qq) {
      const int idx = qq * 256 + tid;            // 2048 half8 = 128x128/8
      const int hf = idx >> 10, inner = idx & 1023;
      const int m2 = inner & 15, ni2 = (inner >> 4) & 3, q2 = (inner >> 6) & 3, ks2 = inner >> 8;
      const int row = hf * 64 + ni2 * 16 + m2;
      const int c8 = ks2 * 4 + q2;               // col/8 in 0..15
      const f16* p = ((c8 >> 3) ? s2 : s1) + row * 64 + (((c8 & 7) ^ (row & 7)) << 3);
      *(half8*)(Sg + (size_t)idx * 8) = *(const half8*)p;
    }
  }
  float4v dacc[2][4] = {};
#pragma unroll
  for (int p = 0; p < 2; ++p)
#pragma unroll
    for (int ks = 0; ks < 2; ++ks) {
      half8 bf[4], af[2];
#pragma unroll
      for (int ni = 0; ni < 4; ++ni) bf[ni] = rdfrag(kuB + p * 4096, ni * 16 + m, ks, q);
#pragma unroll
      for (int mi = 0; mi < 2; ++mi) af[mi] = rdfrag(p ? s2 : s1, w * 32 + mi * 16 + m, ks, q);
#pragma unroll
      for (int mi = 0; mi < 2; ++mi)
#pragma unroll
        for (int ni = 0; ni < 4; ++ni)
          dacc[mi][ni] = __builtin_amdgcn_mfma_f32_16x16x32_f16(af[mi], bf[ni], dacc[mi][ni], 0, 0, 0);
    }
  __syncthreads();
  if (a == b) {
    stage64<128, 256>(qch + ho + (size_t)(a * 128) * DH, DH, quA, tid);
    stage64<128, 256>(vuh + ho + (size_t)(a * 128) * DH, DH, kuB, tid);
  }
  {
    f16* epsD = s1;
#pragma unroll
    for (int mi = 0; mi < 2; ++mi)
#pragma unroll
      for (int ni = 0; ni < 4; ++ni)
#pragma unroll
        for (int r = 0; r < 4; ++r)
          epsD[(w * 32 + mi * 16 + q * 4 + r) * 68 + ni * 16 + m] = (f16)dacc[mi][ni][r];
    __syncthreads();
    // frag-major store: dst = Dg + idx*8 (contiguous)
    f16* Dg = DC + ((size_t)hl * 16 + b) * KD + (size_t)a * 8192;
#pragma unroll
    for (int qq = 0; qq < 4; ++qq) {
      const int idx = qq * 256 + tid;            // 1024 half8 = 128x64/8
      const int pl = idx >> 9, inner = idx & 511;
      const int m2 = inner & 15, ni2 = (inner >> 4) & 3, q2 = (inner >> 6) & 3, ks2 = inner >> 8;
      const int row = pl * 64 + ni2 * 16 + m2;
      const int c = ks2 * 4 + q2;                // 0..7
      *(half8*)(Dg + (size_t)idx * 8) = *(const half8*)(epsD + row * 68 + c * 8);
    }
  }
  if (a == b) {
    float4v tacc[4][4] = {};
    gemm64(quA, kuB, wm, wn, l, tacc);  // qc[a] . vu[a]^T
    f16* Tg = diagb + ((size_t)hl * 16 + a) * TS;
#pragma unroll
    for (int mi = 0; mi < 4; ++mi)
#pragma unroll
      for (int ni = 0; ni < 4; ++ni)
#pragma unroll
        for (int r = 0; r < 4; ++r) {
          const int row = wm + mi * 16 + q * 4 + r, col = wn + ni * 16 + m;
          Tg[(size_t)row * 128 + col] = (col <= row) ? (f16)tacc[mi][ni][r] : (f16)0.f;
        }
  }
}

// In-place exclusive prefix over T: C^{(T)} = sum_{T'<T} D^{(T')}, f32 accumulate.
// Works unchanged on frag-major DC: the frag permutation is within 8KB panels
// (off low 12 bits); a = off>>13 (row/128) is invariant.
__global__ __launch_bounds__(256) void k_scan(f16* __restrict__ DC, int total) {
  const int idx = blockIdx.x * 256 + threadIdx.x;
  if (idx >= total) return;
  const int g = idx >> 17, off = idx & (KD - 1);
  const int a = off >> 13;
  f16* p = DC + (size_t)g * 16 * KD + off;
  float s = 0.f;
#pragma unroll
  for (int T = 0; T < 16; ++T) {
    const float v = (T >= a) ? (float)p[(size_t)T * KD] : 0.f;
    p[(size_t)T * KD] = (f16)s;
    s += v;
  }
}

// Fused scores + online-softmax + PV. Block = (head hl = blockIdx.x [XCD pin],
// 32-row tile mt = 63-y, longest-first: co-resident blocks cluster in ti ->
// shared sig columns stay L2-hot). 4 waves split 64-col jt-chunks.
// ALL B-frag loads use the frag-major layout: one load = 8 cache lines
// (coalesced) instead of 64 (old 128-B-stride gather) -> 8x less TA/L1 line
// traffic, near-zero address VALU (base + immediate).
__global__ __launch_bounds__(256) void k_favs(const f16* __restrict__ qch, const f16* __restrict__ kch,
                                              const f16* __restrict__ DC, const f16* __restrict__ sigb,
                                              const f16* __restrict__ diagb, const f16* __restrict__ vcT,
                                              f16* __restrict__ Oh, int h0) {
  __shared__ float mlds[4][32], llds[4][32];
  __shared__ __align__(16) float olds[32][68];
  __shared__ __align__(16) f16 plds[4][32 * 64];
  const int hl = blockIdx.x, h = h0 + hl;
  const int mt = 63 - (int)blockIdx.y;  // longest-first
  const int tid = threadIdx.x, w = tid >> 6, l = tid & 63;
  const int q = l >> 4, m = l & 15;
  const int ti = mt >> 2, r0 = mt * 32;
  const size_t ho = (size_t)h * N * DH;
  const f16* qc = qch + ho;
  const f16* kcb = kch + ho;                       // frag panels
  const f16* Cb = DC + ((size_t)hl * 16 + ti) * KD; // frag panels
  const f16* Td = diagb + ((size_t)hl * 16 + ti) * TS;
  const f16* Sgb = sigb + (size_t)hl * NTILES * TS; // frag panels
  const f16* V = vcT + (size_t)h * DH * N;          // frag panels
  f16* pw = plds[w];
  const int lo = q * 512 + m * 8;                   // per-lane frag offset

  // cached A-frags: qc rows [r0,r0+32) and T1diag rows (local) [dr,dr+32) x 128 j
  half8 qcA[2][2], tdA[2][4];
  const int dr = (mt & 3) * 32;
#pragma unroll
  for (int mi = 0; mi < 2; ++mi) {
#pragma unroll
    for (int ks = 0; ks < 2; ++ks)
      qcA[mi][ks] = *(const half8*)(qc + (size_t)(r0 + mi * 16 + m) * DH + ks * 32 + q * 8);
#pragma unroll
    for (int ks = 0; ks < 4; ++ks)
      tdA[mi][ks] = *(const half8*)(Td + (size_t)(dr + mi * 16 + m) * 128 + ks * 32 + q * 8);
  }

  float4v o[2][4] = {};
  float mrun[2][4], lrun[2][4];
#pragma unroll
  for (int mi = 0; mi < 2; ++mi)
#pragma unroll
    for (int r = 0; r < 4; ++r) { mrun[mi][r] = -1e30f; lrun[mi][r] = 0.f; }

  const int jtmax = mt >> 1;
  for (int jt = w; jt <= jtmax; jt += 4) {
    const int tkt = jt >> 1;
    const f16* Cp = Cb + (size_t)jt * 4096 + lo;
    const f16* Kp = kcb + (size_t)jt * 4096 + lo;
    const f16* Sp = Sgb + (size_t)PU(tkt, ti) * TS + (size_t)(jt & 1) * 8192 + lo;
    const f16* Vp = V + (size_t)jt * 4096 + lo;
    float4v s[2][4] = {};
    // phase 1: qc . C^{(ti)}[k]^T  (K=64)
#pragma unroll
    for (int ks = 0; ks < 2; ++ks) {
      half8 bf[4];
#pragma unroll
      for (int ni = 0; ni < 4; ++ni) bf[ni] = *(const half8*)(Cp + ks * 2048 + ni * 128);
#pragma unroll
      for (int mi = 0; mi < 2; ++mi)
#pragma unroll
        for (int ni = 0; ni < 4; ++ni)
          s[mi][ni] = __builtin_amdgcn_mfma_f32_16x16x32_f16(qcA[mi][ks], bf[ni], s[mi][ni], 0, 0, 0);
    }
    // phase 2: + T1diag . sig^T  (K=128)
#pragma unroll
    for (int ks = 0; ks < 4; ++ks) {
      half8 bf[4];
#pragma unroll
      for (int ni = 0; ni < 4; ++ni) bf[ni] = *(const half8*)(Sp + ks * 2048 + ni * 128);
#pragma unroll
      for (int mi = 0; mi < 2; ++mi)
#pragma unroll
        for (int ni = 0; ni < 4; ++ni)
          s[mi][ni] = __builtin_amdgcn_mfma_f32_16x16x32_f16(tdA[mi][ks], bf[ni], s[mi][ni], 0, 0, 0);
    }
    // issue V loads early (consumed after the softmax VALU chain)
    half8 bV[2][4];
#pragma unroll
    for (int ks = 0; ks < 2; ++ks)
#pragma unroll
      for (int ni = 0; ni < 4; ++ni) bV[ks][ni] = *(const half8*)(Vp + ks * 2048 + ni * 128);
    // s := -silu(Su)
#pragma unroll
    for (int mi = 0; mi < 2; ++mi)
#pragma unroll
      for (int ni = 0; ni < 4; ++ni)
#pragma unroll
        for (int r = 0; r < 4; ++r) {
          const float x = s[mi][ni][r];
          s[mi][ni][r] = -(x / (1.f + __expf(-x)));
        }
    // phase 3: + Sc = qc . kc^T  (K=64)
#pragma unroll
    for (int ks = 0; ks < 2; ++ks) {
      half8 bf[4];
#pragma unroll
      for (int ni = 0; ni < 4; ++ni) bf[ni] = *(const half8*)(Kp + ks * 2048 + ni * 128);
#pragma unroll
      for (int mi = 0; mi < 2; ++mi)
#pragma unroll
        for (int ni = 0; ni < 4; ++ni)
          s[mi][ni] = __builtin_amdgcn_mfma_f32_16x16x32_f16(qcA[mi][ks], bf[ni], s[mi][ni], 0, 0, 0);
    }
    // causal mask (only the diagonal chunk has cols > some rows)
    if (jt == jtmax) {
      const int k0 = jt * 64;
#pragma unroll
      for (int mi = 0; mi < 2; ++mi)
#pragma unroll
        for (int ni = 0; ni < 4; ++ni) {
          const int col = k0 + ni * 16 + m;
#pragma unroll
          for (int r = 0; r < 4; ++r)
            if (col > r0 + mi * 16 + q * 4 + r) s[mi][ni][r] = -1e30f;
        }
    }
    // online softmax (C-layout: rows = mi*16 + q*4 + r)
    float al[2][4], ts[2][4];
#pragma unroll
    for (int mi = 0; mi < 2; ++mi)
#pragma unroll
      for (int r = 0; r < 4; ++r) {
        float tmx = fmaxf(fmaxf(s[mi][0][r], s[mi][1][r]), fmaxf(s[mi][2][r], s[mi][3][r]));
#pragma unroll
        for (int x = 1; x < 16; x <<= 1) tmx = fmaxf(tmx, __shfl_xor(tmx, x));
        const float nm = fmaxf(mrun[mi][r], tmx);
        al[mi][r] = __expf(mrun[mi][r] - nm);
        mrun[mi][r] = nm;
        ts[mi][r] = 0.f;
      }
#pragma unroll
    for (int mi = 0; mi < 2; ++mi)
#pragma unroll
      for (int ni = 0; ni < 4; ++ni)
#pragma unroll
        for (int r = 0; r < 4; ++r) {
          const float p = __expf(s[mi][ni][r] - mrun[mi][r]);
          wfrag(pw, mi * 16 + q * 4 + r, ni * 16 + m, (f16)p);
          ts[mi][r] += p;
        }
#pragma unroll
    for (int mi = 0; mi < 2; ++mi)
#pragma unroll
      for (int r = 0; r < 4; ++r) {
#pragma unroll
        for (int x = 1; x < 16; x <<= 1) ts[mi][r] += __shfl_xor(ts[mi][r], x);
        lrun[mi][r] = lrun[mi][r] * al[mi][r] + ts[mi][r];
#pragma unroll
        for (int ni = 0; ni < 4; ++ni) o[mi][ni][r] *= al[mi][r];
      }
    // PV: O += P(A-layout via LDS) . vc(bV preloaded before softmax)
#pragma unroll
    for (int ks = 0; ks < 2; ++ks) {
      half8 af[2];
#pragma unroll
      for (int mi = 0; mi < 2; ++mi) af[mi] = rdfrag(pw, mi * 16 + m, ks, q);
#pragma unroll
      for (int mi = 0; mi < 2; ++mi)
#pragma unroll
        for (int ni = 0; ni < 4; ++ni)
          o[mi][ni] = __builtin_amdgcn_mfma_f32_16x16x32_f16(af[mi], bV[ks][ni], o[mi][ni], 0, 0, 0);
    }
  }
  // merge the 4 waves
  if (m == 0)
#pragma unroll
    for (int mi = 0; mi < 2; ++mi)
#pragma unroll
      for (int r = 0; r < 4; ++r) {
        mlds[w][mi * 16 + q * 4 + r] = mrun[mi][r];
        llds[w][mi * 16 + q * 4 + r] = lrun[mi][r];
      }
  __syncthreads();
#pragma unroll
  for (int mi = 0; mi < 2; ++mi)
#pragma unroll
    for (int r = 0; r < 4; ++r) {
      const int row = mi * 16 + q * 4 + r;
      const float mstar = fmaxf(fmaxf(mlds[0][row], mlds[1][row]), fmaxf(mlds[2][row], mlds[3][row]));
      const float sw = __expf(mlds[w][row] - mstar);
#pragma unroll
      for (int ni = 0; ni < 4; ++ni) o[mi][ni][r] *= sw;
    }
#pragma unroll
  for (int t = 0; t < 4; ++t) {
    if (w == t) {
#pragma unroll
      for (int mi = 0; mi < 2; ++mi)
#pragma unroll
        for (int ni = 0; ni < 4; ++ni)
#pragma unroll
          for (int r = 0; r < 4; ++r) {
            const int row = mi * 16 + q * 4 + r, col = ni * 16 + m;
            if (t == 0) olds[row][col] = o[mi][ni][r];
            else olds[row][col] += o[mi][ni][r];
          }
    }
    __syncthreads();
  }
  const int row = tid >> 3, c = tid & 7;
  const float mstar = fmaxf(fmaxf(mlds[0][row], mlds[1][row]), fmaxf(mlds[2][row], mlds[3][row]));
  float denom = 0.f;
#pragma unroll
  for (int t = 0; t < 4; ++t) denom += __expf(mlds[t][row] - mstar) * llds[t][row];
  const float inv = 1.f / denom;
  half8 o8;
#pragma unroll
  for (int e = 0; e < 8; ++e) o8[e] = (f16)(olds[row][c * 8 + e] * inv);
  *(half8*)(Oh + (size_t)(mt * 32 + row) * (H * DH) + h * DH + c * 8) = o8;
}

// out = O @ w_out^T, fp32 result.
__global__ __launch_bounds__(256) void k_out(const f16* __restrict__ Oh, const f16* __restrict__ wo,
                                             float* __restrict__ out) {
  __shared__ __align__(16) f16 lds[128 * LDSH];
  f16* As = lds; f16* Bs = lds + 128 * 64;
  const int tid = threadIdx.x, w = tid >> 6, l = tid & 63;
  const int tm = blockIdx.x * 128, tn = blockIdx.y * 128;
  const int wm = (w >> 1) * 64, wn = (w & 1) * 64;
  float4v acc[4][4] = {};
  for (int k0 = 0; k0 < DIM; k0 += 64) {
    stage64<128, 256>(Oh + (size_t)tm * DIM + k0, DIM, As, tid);
    stage64<128, 256>(wo + (size_t)tn * DIM + k0, DIM, Bs, tid);
    __syncthreads();
    gemm64(As, Bs, wm, wn, l, acc);
    __syncthreads();
  }
  const int rbase = (l >> 4) * 4, cidx = l & 15;
#pragma unroll
  for (int mi = 0; mi < 4; ++mi)
#pragma unroll
    for (int ni = 0; ni < 4; ++ni)
#pragma unroll
      for (int r = 0; r < 4; ++r) {
        const int n = tm + wm + mi * 16 + rbase + r;
        const int dmo = tn + wn + ni * 16 + cidx;
        out[(size_t)n * DIM + dmo] = acc[mi][ni][r];
      }
}

extern "C" void kernel_launch(void* const* d_in, const int* in_sizes, int n_in,
                              void* d_out, int out_size, void* d_ws, size_t ws_size,
                              hipStream_t stream) {
  const float* x = (const float*)d_in[0];
  const float* wqkv = (const float*)d_in[1];
  const float* wout = (const float*)d_in[2];
  float* out = (float*)d_out;
  char* ws = (char*)d_ws;

  size_t off = 0;
  auto alloc = [&](size_t b) { size_t o = off; off += (b + 255) & ~(size_t)255; return o; };
  f16* xh  = (f16*)(ws + alloc((size_t)N * DIM * 2));
  f16* wqh = (f16*)(ws + alloc((size_t)F6 * DIM * 2));
  f16* woh = (f16*)(ws + alloc((size_t)DIM * H * DH * 2));
  f16* quh = (f16*)(ws + alloc((size_t)H * N * DH * 2));
  f16* kuh = (f16*)(ws + alloc((size_t)H * N * DH * 2));
  f16* vuh = (f16*)(ws + alloc((size_t)H * N * DH * 2));
  f16* qch = (f16*)(ws + alloc((size_t)H * N * DH * 2));
  f16* kch = (f16*)(ws + alloc((size_t)H * N * DH * 2));
  f16* vcT = (f16*)(ws + alloc((size_t)H * DH * N * 2));
  f16* vuT = (f16*)(ws + alloc((size_t)H * DH * N * 2));
  f16* Oh  = (f16*)(ws + alloc((size_t)N * H * DH * 2));
  const size_t persist = off;

  // per head: sig tiles + D/C + diag tiles (scob eliminated by k_favs fusion)
  const size_t per_head = ((size_t)NTILES * TS + (size_t)16 * KD + (size_t)16 * TS) * 2;
  int G = (ws_size > persist + 4096) ? (int)((ws_size - persist - 4096) / per_head) : 1;
  if (G < 1) G = 1;
  if (G > 16) G = 16;
  {  // normalize so rounds are evenly sized (prefer G=8 for head->XCD pinning)
    const int R = (H + G - 1) / G;
    G = (H + R - 1) / R;
  }
  f16* sigb  = (f16*)(ws + alloc((size_t)G * NTILES * TS * 2));
  f16* DC    = (f16*)(ws + alloc((size_t)G * 16 * KD * 2));
  f16* diagb = (f16*)(ws + alloc((size_t)G * 16 * TS * 2));

  k_cast<<<(N * DIM / 4 + 255) / 256, 256, 0, stream>>>(x, xh, N * DIM / 4);
  k_cast<<<(F6 * DIM / 4 + 255) / 256, 256, 0, stream>>>(wqkv, wqh, F6 * DIM / 4);
  k_cast<<<(DIM * H * DH / 4 + 255) / 256, 256, 0, stream>>>(wout, woh, DIM * H * DH / 4);

  k_qkv<<<dim3(N / 128, F6 / 128), 256, 0, stream>>>(xh, wqh, quh, kuh, vuh, qch, kch, vcT, vuT);

  for (int h0 = 0; h0 < H; h0 += G) {
    const int Gr = (H - h0 < G) ? (H - h0) : G;
    k_dsig<<<dim3(Gr, 136), 256, 0, stream>>>(quh, kuh, qch, vuh, vuT, sigb, DC, diagb, h0);
    k_scan<<<(Gr * KD + 255) / 256, 256, 0, stream>>>(DC, Gr * KD);
    k_favs<<<dim3(Gr, 64), 256, 0, stream>>>(qch, kch, DC, sigb, diagb, vcT, Oh, h0);
  }

  k_out<<<dim3(16, 8), 256, 0, stream>>>(Oh, woh, out);
}